// Round 7
// baseline (285.228 us; speedup 1.0000x reference)
//
#include <hip/hip_runtime.h>

typedef __bf16 bf16;
typedef __bf16 bf16x8 __attribute__((ext_vector_type(8)));
typedef __bf16 bf16x4 __attribute__((ext_vector_type(4)));
typedef __bf16 bf16x2 __attribute__((ext_vector_type(2)));
typedef float f32x4 __attribute__((ext_vector_type(4)));

static __device__ __forceinline__ bf16x8 ld8(const bf16* p) {
    return *reinterpret_cast<const bf16x8*>(p);
}
static __device__ __forceinline__ bf16x4 ld4(const bf16* p) {
    return *reinterpret_cast<const bf16x4*>(p);
}
// 8-elem LDS load from 4B-aligned address (row stride 74 elems = 148 B)
static __device__ __forceinline__ bf16x8 ld8_b32(const bf16* p) {
    bf16x8 v;
#pragma unroll
    for (int i = 0; i < 4; ++i) {
        bf16x2 t = *reinterpret_cast<const bf16x2*>(p + i * 2);
        v[i * 2] = t[0]; v[i * 2 + 1] = t[1];
    }
    return v;
}
static __device__ __forceinline__ bf16x8 zero8() {
    bf16x8 v;
#pragma unroll
    for (int i = 0; i < 8; ++i) v[i] = (bf16)0.f;
    return v;
}

#define MFMA16(a, b, c) __builtin_amdgcn_mfma_f32_16x16x32_bf16((a), (b), (c), 0, 0, 0)

// ---------------------------------------------------------------------------
// prep: weight fp32->bf16 conversion with pad/scatter, plus bias table gather.
// ---------------------------------------------------------------------------
__global__ __launch_bounds__(256) void prep_kernel(
    const float* __restrict__ kv_w, const float* __restrict__ q_w,
    const float* __restrict__ proj_w, const float* __restrict__ fc1_w,
    const float* __restrict__ fc2_w, const float* __restrict__ rpb,
    const int* __restrict__ rpi,
    bf16* __restrict__ wkv, bf16* __restrict__ wq, bf16* __restrict__ wproj,
    bf16* __restrict__ wfc1, bf16* __restrict__ wfc2, bf16* __restrict__ biast)
{
    int i = blockIdx.x * 256 + threadIdx.x;
    if (i < 73728) {                       // wkv
        int n = i / 192, k = i % 192;
        float v = (n < 360 && k < 180) ? kv_w[n * 180 + k] : 0.f;
        wkv[i] = (bf16)v;
    } else if (i < 122880) {               // wq
        int j = i - 73728; int n = j / 192, k = j % 192;
        float v = (n < 180 && k < 180) ? q_w[n * 180 + k] : 0.f;
        wq[j] = (bf16)v;
    } else if (i < 172032) {               // wproj (head-padded K)
        int j = i - 122880; int n = j / 192, k = j % 192;
        int hh = k >> 5, d = k & 31;
        float v = (n < 180 && d < 30) ? proj_w[n * 180 + hh * 30 + d] : 0.f;
        wproj[j] = (bf16)v;
    } else if (i < 319488) {               // wfc1
        int j = i - 172032; int n = j / 192, k = j % 192;
        float v = (n < 720 && k < 180) ? fc1_w[n * 180 + k] : 0.f;
        wfc1[j] = (bf16)v;
    } else if (i < 507904) {               // wfc2
        int j = i - 319488; int n = j / 736, k = j % 736;
        float v = (n < 180 && k < 720) ? fc2_w[n * 720 + k] : 0.f;
        wfc2[j] = (bf16)v;
    } else if (i < 1392640) {              // bias table [h][q][key]
        int t = i - 507904;
        int h = t / 147456, rem = t % 147456;
        int q = rem / 576, key = rem % 576;
        biast[t] = (bf16)rpb[rpi[q * 576 + key] * 6 + h];
    }
}

// ---------------------------------------------------------------------------
// LayerNorm: one wave per row of 180 fp32 -> bf16 [row][192] (tail zeroed).
// ---------------------------------------------------------------------------
__global__ __launch_bounds__(256) void ln_kernel(
    const float* __restrict__ srcA, const float* __restrict__ srcB,
    const float* __restrict__ g, const float* __restrict__ b,
    bf16* __restrict__ dst)
{
    int wave = threadIdx.x >> 6, lane = threadIdx.x & 63;
    int row = blockIdx.x * 4 + wave;
    const float* sp = (row < 16384) ? (srcA + row * 180) : (srcB + (row - 16384) * 180);
    float v0 = sp[lane];
    float v1 = sp[lane + 64];
    float v2 = (lane < 52) ? sp[lane + 128] : 0.f;
    float s = v0 + v1 + v2;
    float sq = v0 * v0 + v1 * v1 + v2 * v2;
#pragma unroll
    for (int m = 32; m >= 1; m >>= 1) {
        s += __shfl_xor(s, m);
        sq += __shfl_xor(sq, m);
    }
    float mean = s * (1.f / 180.f);
    float var = sq * (1.f / 180.f) - mean * mean;
    float rs = rsqrtf(var + 1e-5f);
    bf16* dp = dst + (long)row * 192;
    dp[lane] = (bf16)((v0 - mean) * rs * g[lane] + b[lane]);
    dp[lane + 64] = (bf16)((v1 - mean) * rs * g[lane + 64] + b[lane + 64]);
    float o2 = (lane < 52) ? ((v2 - mean) * rs * g[lane + 128] + b[lane + 128]) : 0.f;
    dp[lane + 128] = (bf16)o2;
}

// ---------------------------------------------------------------------------
// kv+q projection GEMM v2: wave tile 16x64 (MT=1), 4 waves M-stacked,
// 2-stage register prefetch pipeline. grid = (256, 9).
// ---------------------------------------------------------------------------
__global__ __launch_bounds__(256, 6) void gemm_kvq(
    const bf16* __restrict__ xn, const bf16* __restrict__ yn,
    const bf16* __restrict__ wkv, const bf16* __restrict__ wq,
    const float* __restrict__ kv_b, const float* __restrict__ q_b,
    bf16* __restrict__ kvbuf, bf16* __restrict__ qbuf)
{
    const int tid = threadIdx.x, wave = tid >> 6, lane = tid & 63;
    const int llo = lane & 15, quad = lane >> 4;
    const int ng = blockIdx.y;
    const bool isq = ng >= 6;
    const bf16* A = isq ? yn : xn;
    const bf16* W = isq ? (wq + (ng - 6) * 64 * 192) : (wkv + ng * 64 * 192);
    const int mbase = blockIdx.x * 64 + wave * 16;

    const bf16* Ap = A + (long)(mbase + llo) * 192 + quad * 8;
    const bf16* Wp = W + (long)llo * 192 + quad * 8;

    f32x4 acc[4];
#pragma unroll
    for (int nt = 0; nt < 4; ++nt)
#pragma unroll
        for (int r = 0; r < 4; ++r) acc[nt][r] = 0.f;

    bf16x8 a_cur = ld8(Ap);
    bf16x8 b_cur[4];
#pragma unroll
    for (int nt = 0; nt < 4; ++nt) b_cur[nt] = ld8(Wp + nt * 16 * 192);

#pragma unroll
    for (int kt = 0; kt < 6; ++kt) {
        bf16x8 a_nxt, b_nxt[4];
        if (kt < 5) {
            a_nxt = ld8(Ap + (kt + 1) * 32);
#pragma unroll
            for (int nt = 0; nt < 4; ++nt)
                b_nxt[nt] = ld8(Wp + nt * 16 * 192 + (kt + 1) * 32);
        }
#pragma unroll
        for (int nt = 0; nt < 4; ++nt)
            acc[nt] = MFMA16(a_cur, b_cur[nt], acc[nt]);
        a_cur = a_nxt;
#pragma unroll
        for (int nt = 0; nt < 4; ++nt) b_cur[nt] = b_nxt[nt];
    }

#pragma unroll
    for (int nt = 0; nt < 4; ++nt)
#pragma unroll
        for (int r = 0; r < 4; ++r) {
            int m = mbase + quad * 4 + r;
            int n = ng * 64 + nt * 16 + llo;
            if (!isq) {
                if (n < 360) {
                    float v = acc[nt][r] + kv_b[n];
                    int nn = n % 180;
                    int col = (n / 180) * 192 + (nn / 30) * 32 + (nn % 30);
                    kvbuf[(long)m * 384 + col] = (bf16)v;
                }
            } else {
                int nq = n - 384;
                if (nq < 180) {
                    float v = (acc[nt][r] + q_b[nq]) * 0.18257418583505537f;
                    int col = (nq / 30) * 32 + (nq % 30);
                    qbuf[(long)m * 192 + col] = (bf16)v;
                }
            }
        }
}

// ---------------------------------------------------------------------------
// Attention v6 (unchanged from round 6): transposed-S, LDS-staged K/V with
// register prefetch, Vt stride 74.
// ---------------------------------------------------------------------------
__global__ __launch_bounds__(512, 6) void attn_kernel(
    const bf16* __restrict__ qbuf,   // [16384][192] head-padded, pre-scaled
    const bf16* __restrict__ kvbuf,  // [16384][384] K at +0, V at +192
    const bf16* __restrict__ biast,  // [6][256][576]
    bf16* __restrict__ obuf)         // [16384][192] head-padded
{
    const int qhalf = blockIdx.x & 1;
    const int head = (blockIdx.x >> 1) % 6;
    const int win = blockIdx.x / 12;
    const int bb = win / 16, wi = (win % 16) / 4, wj = win % 4;
    const int tid = threadIdx.x;
    const int wave = tid >> 6, lane = tid & 63;
    const int llo = lane & 15, quad = lane >> 4;
    const int qbase = qhalf * 128 + wave * 16;

    __shared__ bf16 Kc[64][40];
    __shared__ bf16 Vt[32][74];
    __shared__ bf16 Ps[8][16][72];

    const int u = tid & 255;
    const int tloc = u >> 2, dq = u & 3;
    const bool isV = tid >= 256;
    int aa = tloc / 24, w0 = tloc % 24;

    const int q0 = qbase + llo;
    const int gr_q = bb * 4096 + (wi * 16 + (q0 >> 4)) * 64 + (wj * 16 + (q0 & 15));
    const bf16x8 qf = ld8(qbuf + (long)gr_q * 192 + head * 32 + quad * 8);

    bf16x8 stage = zero8();
    {
        int gy = wi * 16 + aa - 4, gx = wj * 16 + w0 - 4;
        if ((unsigned)gy < 64u && (unsigned)gx < 64u) {
            long gr = (long)(bb * 4096 + gy * 64 + gx) * 384;
            stage = ld8(kvbuf + gr + (isV ? 192 : 0) + head * 32 + dq * 8);
        }
    }

    f32x4 o[2];
    float m_run = -1e30f, l_run = 0.f;
#pragma unroll
    for (int n2 = 0; n2 < 2; ++n2)
#pragma unroll
        for (int r = 0; r < 4; ++r) o[n2][r] = 0.f;

    for (int c = 0; c < 9; ++c) {
        const int kb = c * 64;
        __syncthreads();
        if (!isV) {
            *reinterpret_cast<bf16x8*>(&Kc[tloc][dq * 8]) = stage;
        } else {
#pragma unroll
            for (int j = 0; j < 8; ++j) Vt[dq * 8 + j][tloc] = stage[j];
        }
        __syncthreads();

        if (c < 8) {
            w0 += 16; aa += 2;
            if (w0 >= 24) { w0 -= 24; ++aa; }
            int gy = wi * 16 + aa - 4, gx = wj * 16 + w0 - 4;
            stage = zero8();
            if ((unsigned)gy < 64u && (unsigned)gx < 64u) {
                long gr = (long)(bb * 4096 + gy * 64 + gx) * 384;
                stage = ld8(kvbuf + gr + (isV ? 192 : 0) + head * 32 + dq * 8);
            }
        }

        f32x4 s[4];
#pragma unroll
        for (int kt = 0; kt < 4; ++kt) {
            bf16x8 kf = ld8(&Kc[kt * 16 + llo][quad * 8]);
            f32x4 zc;
            zc[0] = 0.f; zc[1] = 0.f; zc[2] = 0.f; zc[3] = 0.f;
            s[kt] = MFMA16(kf, qf, zc);
        }

#pragma unroll
        for (int kt = 0; kt < 4; ++kt) {
            bf16x4 bv = ld4(biast + ((long)head * 256 + q0) * 576 + kb + kt * 16 + quad * 4);
#pragma unroll
            for (int r = 0; r < 4; ++r) s[kt][r] += (float)bv[r];
        }

        float mx = s[0][0];
#pragma unroll
        for (int kt = 0; kt < 4; ++kt)
#pragma unroll
            for (int r = 0; r < 4; ++r) mx = fmaxf(mx, s[kt][r]);
        mx = fmaxf(mx, __shfl_xor(mx, 16));
        mx = fmaxf(mx, __shfl_xor(mx, 32));
        float m_new = fmaxf(m_run, mx);
        float alpha = __expf(m_run - m_new);
        float ls = 0.f;
#pragma unroll
        for (int kt = 0; kt < 4; ++kt)
#pragma unroll
            for (int r = 0; r < 4; ++r) {
                float p = __expf(s[kt][r] - m_new);
                s[kt][r] = p;
                ls += p;
            }
        ls += __shfl_xor(ls, 16);
        ls += __shfl_xor(ls, 32);
        l_run = l_run * alpha + ls;
        m_run = m_new;

#pragma unroll
        for (int r = 0; r < 4; ++r) {
            float a = __shfl(alpha, quad * 4 + r);
            o[0][r] *= a;
            o[1][r] *= a;
        }

#pragma unroll
        for (int kt = 0; kt < 4; ++kt) {
            bf16x4 pv;
#pragma unroll
            for (int r = 0; r < 4; ++r) pv[r] = (bf16)s[kt][r];
            *reinterpret_cast<bf16x4*>(&Ps[wave][llo][kt * 16 + quad * 4]) = pv;
        }

#pragma unroll
        for (int kt2 = 0; kt2 < 2; ++kt2) {
            bf16x8 pa = ld8(&Ps[wave][llo][kt2 * 32 + quad * 8]);
#pragma unroll
            for (int n2 = 0; n2 < 2; ++n2) {
                bf16x8 vb = ld8_b32(&Vt[n2 * 16 + llo][kt2 * 32 + quad * 8]);
                o[n2] = MFMA16(pa, vb, o[n2]);
            }
        }
    }

    float linv = 1.f / l_run;
#pragma unroll
    for (int r = 0; r < 4; ++r) {
        float li = __shfl(linv, quad * 4 + r);
        int q = qbase + quad * 4 + r;
        int gr = bb * 4096 + (wi * 16 + (q >> 4)) * 64 + (wj * 16 + (q & 15));
#pragma unroll
        for (int n2 = 0; n2 < 2; ++n2)
            obuf[(long)gr * 192 + head * 32 + n2 * 16 + llo] = (bf16)(o[n2][r] * li);
    }
}

// ---------------------------------------------------------------------------
// Fused proj + bias + residual + LayerNorm2. Grid-capped at 1024 waves, so
// maximize per-wave ILP: all 6 A-frags hoisted; B-loads free to batch.
// ---------------------------------------------------------------------------
__global__ __launch_bounds__(256, 2) void gemm_projln(
    const bf16* __restrict__ obuf, const bf16* __restrict__ wproj,
    const float* __restrict__ proj_b, const float* __restrict__ x,
    const float* __restrict__ g, const float* __restrict__ bln,
    float* __restrict__ xo, bf16* __restrict__ xn2)
{
    const int tid = threadIdx.x, wave = tid >> 6, lane = tid & 63;
    const int llo = lane & 15, quad = lane >> 4;
    const int mbase = blockIdx.x * 64 + wave * 16;

    bf16x8 a[6];
#pragma unroll
    for (int kt = 0; kt < 6; ++kt)
        a[kt] = ld8(obuf + (long)(mbase + llo) * 192 + kt * 32 + quad * 8);

    f32x4 acc[12];
#pragma unroll
    for (int nt = 0; nt < 12; ++nt)
#pragma unroll
        for (int r = 0; r < 4; ++r) acc[nt][r] = 0.f;

#pragma unroll
    for (int nt = 0; nt < 12; ++nt)
#pragma unroll
        for (int kt = 0; kt < 6; ++kt) {
            bf16x8 bb = ld8(wproj + (long)(nt * 16 + llo) * 192 + kt * 32 + quad * 8);
            acc[nt] = MFMA16(a[kt], bb, acc[nt]);
        }

#pragma unroll
    for (int r = 0; r < 4; ++r) {
        int m = mbase + quad * 4 + r;
        float v[12];
        float sum = 0.f, sq = 0.f;
#pragma unroll
        for (int nt = 0; nt < 12; ++nt) {
            int n = nt * 16 + llo;
            float val = 0.f;
            if (n < 180) val = acc[nt][r] + proj_b[n] + x[(long)m * 180 + n];
            v[nt] = val;
            sum += val; sq += val * val;
        }
#pragma unroll
        for (int msk = 1; msk <= 8; msk <<= 1) {
            sum += __shfl_xor(sum, msk);
            sq  += __shfl_xor(sq, msk);
        }
        float mean = sum * (1.f / 180.f);
        float var = sq * (1.f / 180.f) - mean * mean;
        float rs = rsqrtf(var + 1e-5f);
#pragma unroll
        for (int nt = 0; nt < 12; ++nt) {
            int n = nt * 16 + llo;
            if (n < 180) {
                xo[(long)m * 180 + n] = v[nt];
                xn2[(long)m * 192 + n] = (bf16)((v[nt] - mean) * rs * g[n] + bln[n]);
            } else {
                xn2[(long)m * 192 + n] = (bf16)0.f;
            }
        }
    }
}

// ---------------------------------------------------------------------------
// Epilogue GEMM v3: wave tile 16 x (NT*16), 4 waves M-stacked (block 64 rows),
// 2-stage register prefetch pipeline over K.
// MODE 2: fp32 out = v + resid; MODE 3: bf16 out = gelu(v).
// ---------------------------------------------------------------------------
template <int NT, int KPAD, int NREAL, int OSTRIDE, int MODE>
__global__ __launch_bounds__(256, 6) void gemm_ep(
    const bf16* __restrict__ A, const bf16* __restrict__ W,
    const float* __restrict__ bias, const float* __restrict__ resid,
    void* __restrict__ outp)
{
    const int tid = threadIdx.x, wave = tid >> 6, lane = tid & 63;
    const int llo = lane & 15, quad = lane >> 4;
    const int mbase = blockIdx.x * 64 + wave * 16;
    const int nbase = blockIdx.y * (NT * 16);
    constexpr int NK = KPAD / 32;

    const bf16* Ap = A + (long)(mbase + llo) * KPAD + quad * 8;
    const bf16* Wp = W + (long)(nbase + llo) * KPAD + quad * 8;

    f32x4 acc[NT];
#pragma unroll
    for (int nt = 0; nt < NT; ++nt)
#pragma unroll
        for (int r = 0; r < 4; ++r) acc[nt][r] = 0.f;

    bf16x8 a_cur = ld8(Ap);
    bf16x8 b_cur[NT];
#pragma unroll
    for (int nt = 0; nt < NT; ++nt) b_cur[nt] = ld8(Wp + (long)nt * 16 * KPAD);

#pragma unroll
    for (int kt = 0; kt < NK; ++kt) {
        bf16x8 a_nxt, b_nxt[NT];
        if (kt < NK - 1) {
            a_nxt = ld8(Ap + (kt + 1) * 32);
#pragma unroll
            for (int nt = 0; nt < NT; ++nt)
                b_nxt[nt] = ld8(Wp + (long)nt * 16 * KPAD + (kt + 1) * 32);
        }
#pragma unroll
        for (int nt = 0; nt < NT; ++nt)
            acc[nt] = MFMA16(a_cur, b_cur[nt], acc[nt]);
        a_cur = a_nxt;
#pragma unroll
        for (int nt = 0; nt < NT; ++nt) b_cur[nt] = b_nxt[nt];
    }

#pragma unroll
    for (int nt = 0; nt < NT; ++nt)
#pragma unroll
        for (int r = 0; r < 4; ++r) {
            int m = mbase + quad * 4 + r;
            int n = nbase + nt * 16 + llo;
            if (n >= NREAL) continue;
            float v = acc[nt][r] + bias[n];
            if (MODE == 2) {
                ((float*)outp)[(long)m * OSTRIDE + n] = v + resid[(long)m * 180 + n];
            } else {
                float gel = 0.5f * v * (1.f + erff(v * 0.7071067811865475f));
                ((bf16*)outp)[(long)m * OSTRIDE + n] = (bf16)gel;
            }
        }
}

// ---------------------------------------------------------------------------
extern "C" void kernel_launch(void* const* d_in, const int* in_sizes, int n_in,
                              void* d_out, int out_size, void* d_ws, size_t ws_size,
                              hipStream_t stream) {
    const float* x      = (const float*)d_in[0];
    const float* y      = (const float*)d_in[1];
    const float* n1g    = (const float*)d_in[2];
    const float* n1b    = (const float*)d_in[3];
    const float* kv_w   = (const float*)d_in[4];
    const float* kv_b   = (const float*)d_in[5];
    const float* q_w    = (const float*)d_in[6];
    const float* q_b    = (const float*)d_in[7];
    const float* rpb    = (const float*)d_in[8];
    const float* proj_w = (const float*)d_in[9];
    const float* proj_b = (const float*)d_in[10];
    const float* n2g    = (const float*)d_in[11];
    const float* n2b    = (const float*)d_in[12];
    const float* fc1_w  = (const float*)d_in[13];
    const float* fc1_b  = (const float*)d_in[14];
    const float* fc2_w  = (const float*)d_in[15];
    const float* fc2_b  = (const float*)d_in[16];
    const int*   rpi    = (const int*)d_in[17];

    char* ws = (char*)d_ws;
    bf16* xn    = (bf16*)(ws + 0);          // [32768][192] = xn (16384) + yn (16384)
    bf16* yn    = (bf16*)(ws + 6291456);
    bf16* qbuf  = (bf16*)(ws + 12582912);   // [16384][192]
    bf16* kvbuf = (bf16*)(ws + 18874368);   // [16384][384]
    bf16* obuf  = (bf16*)(ws + 31457280);   // [16384][192]
    float* xo   = (float*)(ws + 37748736);  // [16384][180] fp32
    bf16* biast = (bf16*)(ws + 49545216);   // [6][256][576]
    bf16* wkv   = (bf16*)(ws + 51314688);
    bf16* wq    = (bf16*)(ws + 51462144);
    bf16* wproj = (bf16*)(ws + 51560448);
    bf16* wfc1  = (bf16*)(ws + 51658752);
    bf16* wfc2  = (bf16*)(ws + 51953664);
    bf16* hmid  = (bf16*)(ws + 6291456);    // reuse yn/qbuf/kvbuf (dead post-attn)
    bf16* xn2   = xn;                       // xn dead after gemm_kvq

    prep_kernel<<<5440, 256, 0, stream>>>(kv_w, q_w, proj_w, fc1_w, fc2_w, rpb, rpi,
                                          wkv, wq, wproj, wfc1, wfc2, biast);
    ln_kernel<<<8192, 256, 0, stream>>>(x, y, n1g, n1b, xn);
    gemm_kvq<<<dim3(256, 9), 256, 0, stream>>>(xn, yn, wkv, wq, kv_b, q_b, kvbuf, qbuf);
    attn_kernel<<<768, 512, 0, stream>>>(qbuf, kvbuf, biast, obuf);
    gemm_projln<<<256, 256, 0, stream>>>(obuf, wproj, proj_b, x, n2g, n2b, xo, xn2);
    gemm_ep<4, 192, 720, 736, 3><<<dim3(256, 12), 256, 0, stream>>>(xn2, wfc1, fc1_b, nullptr, hmid);
    gemm_ep<2, 736, 180, 180, 2><<<dim3(256, 6), 256, 0, stream>>>(hmid, wfc2, fc2_b, xo, (float*)d_out);
}

// Round 8
// 221.536 us; speedup vs baseline: 1.2875x; 1.2875x over previous
//
#include <hip/hip_runtime.h>

typedef __bf16 bf16;
typedef __bf16 bf16x8 __attribute__((ext_vector_type(8)));
typedef __bf16 bf16x4 __attribute__((ext_vector_type(4)));
typedef __bf16 bf16x2 __attribute__((ext_vector_type(2)));
typedef float f32x4 __attribute__((ext_vector_type(4)));

static __device__ __forceinline__ bf16x8 ld8(const bf16* p) {
    return *reinterpret_cast<const bf16x8*>(p);
}
static __device__ __forceinline__ bf16x4 ld4(const bf16* p) {
    return *reinterpret_cast<const bf16x4*>(p);
}
static __device__ __forceinline__ bf16x8 ld8_b32(const bf16* p) {
    bf16x8 v;
#pragma unroll
    for (int i = 0; i < 4; ++i) {
        bf16x2 t = *reinterpret_cast<const bf16x2*>(p + i * 2);
        v[i * 2] = t[0]; v[i * 2 + 1] = t[1];
    }
    return v;
}
static __device__ __forceinline__ bf16x8 zero8() {
    bf16x8 v;
#pragma unroll
    for (int i = 0; i < 8; ++i) v[i] = (bf16)0.f;
    return v;
}

#define MFMA16(a, b, c) __builtin_amdgcn_mfma_f32_16x16x32_bf16((a), (b), (c), 0, 0, 0)

// Stage a 64-row x BK-elem tile (row stride KPAD elems in global) into LDS
// with row stride 200 elems. 256 threads, fully coalesced 16B chunks.
// Read-side bank classes (llo*100+kt*16+quad*4) mod 32 -> 8 classes x 8 lanes
// -> conflict-free ds_read_b128.
template <int BK, int KPAD>
static __device__ __forceinline__ void stage_tile(const bf16* __restrict__ g,
                                                  bf16* __restrict__ lds, int tid) {
    constexpr int CPR = BK / 8;            // 16B chunks per row
    constexpr int NP = 64 * CPR / 256;     // passes
#pragma unroll
    for (int p = 0; p < NP; ++p) {
        int idx = p * 256 + tid;
        int row = idx / CPR, cg = idx % CPR;
        bf16x8 v = ld8(g + (long)row * KPAD + cg * 8);
        *reinterpret_cast<bf16x8*>(lds + row * 200 + cg * 8) = v;
    }
}

// ---------------------------------------------------------------------------
// prep: weight fp32->bf16 conversion with pad/scatter, plus bias table gather.
// ---------------------------------------------------------------------------
__global__ __launch_bounds__(256) void prep_kernel(
    const float* __restrict__ kv_w, const float* __restrict__ q_w,
    const float* __restrict__ proj_w, const float* __restrict__ fc1_w,
    const float* __restrict__ fc2_w, const float* __restrict__ rpb,
    const int* __restrict__ rpi,
    bf16* __restrict__ wkv, bf16* __restrict__ wq, bf16* __restrict__ wproj,
    bf16* __restrict__ wfc1, bf16* __restrict__ wfc2, bf16* __restrict__ biast)
{
    int i = blockIdx.x * 256 + threadIdx.x;
    if (i < 73728) {                       // wkv
        int n = i / 192, k = i % 192;
        float v = (n < 360 && k < 180) ? kv_w[n * 180 + k] : 0.f;
        wkv[i] = (bf16)v;
    } else if (i < 122880) {               // wq
        int j = i - 73728; int n = j / 192, k = j % 192;
        float v = (n < 180 && k < 180) ? q_w[n * 180 + k] : 0.f;
        wq[j] = (bf16)v;
    } else if (i < 172032) {               // wproj (head-padded K)
        int j = i - 122880; int n = j / 192, k = j % 192;
        int hh = k >> 5, d = k & 31;
        float v = (n < 180 && d < 30) ? proj_w[n * 180 + hh * 30 + d] : 0.f;
        wproj[j] = (bf16)v;
    } else if (i < 319488) {               // wfc1
        int j = i - 172032; int n = j / 192, k = j % 192;
        float v = (n < 720 && k < 180) ? fc1_w[n * 180 + k] : 0.f;
        wfc1[j] = (bf16)v;
    } else if (i < 507904) {               // wfc2
        int j = i - 319488; int n = j / 736, k = j % 736;
        float v = (n < 180 && k < 720) ? fc2_w[n * 720 + k] : 0.f;
        wfc2[j] = (bf16)v;
    } else if (i < 1392640) {              // bias table [h][q][key]
        int t = i - 507904;
        int h = t / 147456, rem = t % 147456;
        int q = rem / 576, key = rem % 576;
        biast[t] = (bf16)rpb[rpi[q * 576 + key] * 6 + h];
    }
}

// ---------------------------------------------------------------------------
// LayerNorm: one wave per row of 180 fp32 -> bf16 [row][192] (tail zeroed).
// ---------------------------------------------------------------------------
__global__ __launch_bounds__(256) void ln_kernel(
    const float* __restrict__ srcA, const float* __restrict__ srcB,
    const float* __restrict__ g, const float* __restrict__ b,
    bf16* __restrict__ dst)
{
    int wave = threadIdx.x >> 6, lane = threadIdx.x & 63;
    int row = blockIdx.x * 4 + wave;
    const float* sp = (row < 16384) ? (srcA + row * 180) : (srcB + (row - 16384) * 180);
    float v0 = sp[lane];
    float v1 = sp[lane + 64];
    float v2 = (lane < 52) ? sp[lane + 128] : 0.f;
    float s = v0 + v1 + v2;
    float sq = v0 * v0 + v1 * v1 + v2 * v2;
#pragma unroll
    for (int m = 32; m >= 1; m >>= 1) {
        s += __shfl_xor(s, m);
        sq += __shfl_xor(sq, m);
    }
    float mean = s * (1.f / 180.f);
    float var = sq * (1.f / 180.f) - mean * mean;
    float rs = rsqrtf(var + 1e-5f);
    bf16* dp = dst + (long)row * 192;
    dp[lane] = (bf16)((v0 - mean) * rs * g[lane] + b[lane]);
    dp[lane + 64] = (bf16)((v1 - mean) * rs * g[lane + 64] + b[lane + 64]);
    float o2 = (lane < 52) ? ((v2 - mean) * rs * g[lane + 128] + b[lane + 128]) : 0.f;
    dp[lane + 128] = (bf16)o2;
}

// ---------------------------------------------------------------------------
// kv+q projection GEMM, LDS-staged: block tile 64x64, K=192 staged whole.
// grid = (256, 9): ng 0..5 -> kv (N=384), ng 6..8 -> q (N=192).
// ---------------------------------------------------------------------------
__global__ __launch_bounds__(256, 3) void gemm_kvq(
    const bf16* __restrict__ xn, const bf16* __restrict__ yn,
    const bf16* __restrict__ wkv, const bf16* __restrict__ wq,
    const float* __restrict__ kv_b, const float* __restrict__ q_b,
    bf16* __restrict__ kvbuf, bf16* __restrict__ qbuf)
{
    const int tid = threadIdx.x, wave = tid >> 6, lane = tid & 63;
    const int llo = lane & 15, quad = lane >> 4;
    const int ng = blockIdx.y;
    const bool isq = ng >= 6;
    const bf16* A = isq ? yn : xn;
    const bf16* W = isq ? (wq + (ng - 6) * 64 * 192) : (wkv + ng * 64 * 192);
    const int tm = blockIdx.x * 64;

    __shared__ __align__(16) bf16 Sa[64 * 200];
    __shared__ __align__(16) bf16 Sb[64 * 200];
    stage_tile<192, 192>(A + (long)tm * 192, Sa, tid);
    stage_tile<192, 192>(W, Sb, tid);
    __syncthreads();

    f32x4 acc[4];
#pragma unroll
    for (int nt = 0; nt < 4; ++nt)
#pragma unroll
        for (int r = 0; r < 4; ++r) acc[nt][r] = 0.f;

#pragma unroll
    for (int kt = 0; kt < 6; ++kt) {
        bf16x8 a = ld8(Sa + (wave * 16 + llo) * 200 + kt * 32 + quad * 8);
#pragma unroll
        for (int nt = 0; nt < 4; ++nt) {
            bf16x8 b = ld8(Sb + (nt * 16 + llo) * 200 + kt * 32 + quad * 8);
            acc[nt] = MFMA16(a, b, acc[nt]);
        }
    }

#pragma unroll
    for (int nt = 0; nt < 4; ++nt)
#pragma unroll
        for (int r = 0; r < 4; ++r) {
            int m = tm + wave * 16 + quad * 4 + r;
            int n = ng * 64 + nt * 16 + llo;
            if (!isq) {
                if (n < 360) {
                    float v = acc[nt][r] + kv_b[n];
                    int nn = n % 180;
                    int col = (n / 180) * 192 + (nn / 30) * 32 + (nn % 30);
                    kvbuf[(long)m * 384 + col] = (bf16)v;
                }
            } else {
                int nq = n - 384;
                if (nq < 180) {
                    float v = (acc[nt][r] + q_b[nq]) * 0.18257418583505537f;
                    int col = (nq / 30) * 32 + (nq % 30);
                    qbuf[(long)m * 192 + col] = (bf16)v;
                }
            }
        }
}

// ---------------------------------------------------------------------------
// Attention v6 (unchanged): transposed-S, LDS-staged K/V with reg prefetch.
// ---------------------------------------------------------------------------
__global__ __launch_bounds__(512, 6) void attn_kernel(
    const bf16* __restrict__ qbuf, const bf16* __restrict__ kvbuf,
    const bf16* __restrict__ biast, bf16* __restrict__ obuf)
{
    const int qhalf = blockIdx.x & 1;
    const int head = (blockIdx.x >> 1) % 6;
    const int win = blockIdx.x / 12;
    const int bb = win / 16, wi = (win % 16) / 4, wj = win % 4;
    const int tid = threadIdx.x;
    const int wave = tid >> 6, lane = tid & 63;
    const int llo = lane & 15, quad = lane >> 4;
    const int qbase = qhalf * 128 + wave * 16;

    __shared__ bf16 Kc[64][40];
    __shared__ bf16 Vt[32][74];
    __shared__ bf16 Ps[8][16][72];

    const int u = tid & 255;
    const int tloc = u >> 2, dq = u & 3;
    const bool isV = tid >= 256;
    int aa = tloc / 24, w0 = tloc % 24;

    const int q0 = qbase + llo;
    const int gr_q = bb * 4096 + (wi * 16 + (q0 >> 4)) * 64 + (wj * 16 + (q0 & 15));
    const bf16x8 qf = ld8(qbuf + (long)gr_q * 192 + head * 32 + quad * 8);

    bf16x8 stage = zero8();
    {
        int gy = wi * 16 + aa - 4, gx = wj * 16 + w0 - 4;
        if ((unsigned)gy < 64u && (unsigned)gx < 64u) {
            long gr = (long)(bb * 4096 + gy * 64 + gx) * 384;
            stage = ld8(kvbuf + gr + (isV ? 192 : 0) + head * 32 + dq * 8);
        }
    }

    f32x4 o[2];
    float m_run = -1e30f, l_run = 0.f;
#pragma unroll
    for (int n2 = 0; n2 < 2; ++n2)
#pragma unroll
        for (int r = 0; r < 4; ++r) o[n2][r] = 0.f;

    for (int c = 0; c < 9; ++c) {
        const int kb = c * 64;
        __syncthreads();
        if (!isV) {
            *reinterpret_cast<bf16x8*>(&Kc[tloc][dq * 8]) = stage;
        } else {
#pragma unroll
            for (int j = 0; j < 8; ++j) Vt[dq * 8 + j][tloc] = stage[j];
        }
        __syncthreads();

        if (c < 8) {
            w0 += 16; aa += 2;
            if (w0 >= 24) { w0 -= 24; ++aa; }
            int gy = wi * 16 + aa - 4, gx = wj * 16 + w0 - 4;
            stage = zero8();
            if ((unsigned)gy < 64u && (unsigned)gx < 64u) {
                long gr = (long)(bb * 4096 + gy * 64 + gx) * 384;
                stage = ld8(kvbuf + gr + (isV ? 192 : 0) + head * 32 + dq * 8);
            }
        }

        f32x4 s[4];
#pragma unroll
        for (int kt = 0; kt < 4; ++kt) {
            bf16x8 kf = ld8(&Kc[kt * 16 + llo][quad * 8]);
            f32x4 zc;
            zc[0] = 0.f; zc[1] = 0.f; zc[2] = 0.f; zc[3] = 0.f;
            s[kt] = MFMA16(kf, qf, zc);
        }

#pragma unroll
        for (int kt = 0; kt < 4; ++kt) {
            bf16x4 bv = ld4(biast + ((long)head * 256 + q0) * 576 + kb + kt * 16 + quad * 4);
#pragma unroll
            for (int r = 0; r < 4; ++r) s[kt][r] += (float)bv[r];
        }

        float mx = s[0][0];
#pragma unroll
        for (int kt = 0; kt < 4; ++kt)
#pragma unroll
            for (int r = 0; r < 4; ++r) mx = fmaxf(mx, s[kt][r]);
        mx = fmaxf(mx, __shfl_xor(mx, 16));
        mx = fmaxf(mx, __shfl_xor(mx, 32));
        float m_new = fmaxf(m_run, mx);
        float alpha = __expf(m_run - m_new);
        float ls = 0.f;
#pragma unroll
        for (int kt = 0; kt < 4; ++kt)
#pragma unroll
            for (int r = 0; r < 4; ++r) {
                float p = __expf(s[kt][r] - m_new);
                s[kt][r] = p;
                ls += p;
            }
        ls += __shfl_xor(ls, 16);
        ls += __shfl_xor(ls, 32);
        l_run = l_run * alpha + ls;
        m_run = m_new;

#pragma unroll
        for (int r = 0; r < 4; ++r) {
            float a = __shfl(alpha, quad * 4 + r);
            o[0][r] *= a;
            o[1][r] *= a;
        }

#pragma unroll
        for (int kt = 0; kt < 4; ++kt) {
            bf16x4 pv;
#pragma unroll
            for (int r = 0; r < 4; ++r) pv[r] = (bf16)s[kt][r];
            *reinterpret_cast<bf16x4*>(&Ps[wave][llo][kt * 16 + quad * 4]) = pv;
        }

#pragma unroll
        for (int kt2 = 0; kt2 < 2; ++kt2) {
            bf16x8 pa = ld8(&Ps[wave][llo][kt2 * 32 + quad * 8]);
#pragma unroll
            for (int n2 = 0; n2 < 2; ++n2) {
                bf16x8 vb = ld8_b32(&Vt[n2 * 16 + llo][kt2 * 32 + quad * 8]);
                o[n2] = MFMA16(pa, vb, o[n2]);
            }
        }
    }

    float linv = 1.f / l_run;
#pragma unroll
    for (int r = 0; r < 4; ++r) {
        float li = __shfl(linv, quad * 4 + r);
        int q = qbase + quad * 4 + r;
        int gr = bb * 4096 + (wi * 16 + (q >> 4)) * 64 + (wj * 16 + (q & 15));
#pragma unroll
        for (int n2 = 0; n2 < 2; ++n2)
            obuf[(long)gr * 192 + head * 32 + n2 * 16 + llo] = (bf16)(o[n2][r] * li);
    }
}

// ---------------------------------------------------------------------------
// Fused proj + bias + residual + LN2, LDS-staged. Block = 64 rows; A staged
// once, W staged in 3 n-chunks of 64. Wave owns 16 rows x all 192 cols.
// ---------------------------------------------------------------------------
__global__ __launch_bounds__(256, 3) void gemm_projln(
    const bf16* __restrict__ obuf, const bf16* __restrict__ wproj,
    const float* __restrict__ proj_b, const float* __restrict__ x,
    const float* __restrict__ g, const float* __restrict__ bln,
    float* __restrict__ xo, bf16* __restrict__ xn2)
{
    const int tid = threadIdx.x, wave = tid >> 6, lane = tid & 63;
    const int llo = lane & 15, quad = lane >> 4;
    const int mbase = blockIdx.x * 64;

    __shared__ __align__(16) bf16 Sa[64 * 200];
    __shared__ __align__(16) bf16 Sb[64 * 200];
    stage_tile<192, 192>(obuf + (long)mbase * 192, Sa, tid);

    f32x4 acc[12];
#pragma unroll
    for (int nt = 0; nt < 12; ++nt)
#pragma unroll
        for (int r = 0; r < 4; ++r) acc[nt][r] = 0.f;

    for (int nc = 0; nc < 3; ++nc) {
        if (nc) __syncthreads();
        stage_tile<192, 192>(wproj + (long)nc * 64 * 192, Sb, tid);
        __syncthreads();
#pragma unroll
        for (int kt = 0; kt < 6; ++kt) {
            bf16x8 a = ld8(Sa + (wave * 16 + llo) * 200 + kt * 32 + quad * 8);
#pragma unroll
            for (int nt = 0; nt < 4; ++nt) {
                bf16x8 b = ld8(Sb + (nt * 16 + llo) * 200 + kt * 32 + quad * 8);
                acc[nc * 4 + nt] = MFMA16(a, b, acc[nc * 4 + nt]);
            }
        }
    }

#pragma unroll
    for (int r = 0; r < 4; ++r) {
        int m = mbase + wave * 16 + quad * 4 + r;
        float v[12];
        float sum = 0.f, sq = 0.f;
#pragma unroll
        for (int nt = 0; nt < 12; ++nt) {
            int n = nt * 16 + llo;
            float val = 0.f;
            if (n < 180) val = acc[nt][r] + proj_b[n] + x[(long)m * 180 + n];
            v[nt] = val;
            sum += val; sq += val * val;
        }
#pragma unroll
        for (int msk = 1; msk <= 8; msk <<= 1) {
            sum += __shfl_xor(sum, msk);
            sq  += __shfl_xor(sq, msk);
        }
        float mean = sum * (1.f / 180.f);
        float var = sq * (1.f / 180.f) - mean * mean;
        float rs = rsqrtf(var + 1e-5f);
#pragma unroll
        for (int nt = 0; nt < 12; ++nt) {
            int n = nt * 16 + llo;
            if (n < 180) {
                xo[(long)m * 180 + n] = v[nt];
                xn2[(long)m * 192 + n] = (bf16)((v[nt] - mean) * rs * g[n] + bln[n]);
            } else {
                xn2[(long)m * 192 + n] = (bf16)0.f;
            }
        }
    }
}

// ---------------------------------------------------------------------------
// Epilogue GEMM, LDS-staged: block tile 64x64; K chunked 192,192,192,160.
// MODE 2: fp32 out = v + resid; MODE 3: bf16 out = gelu(v).
// ---------------------------------------------------------------------------
template <int KPAD, int NREAL, int OSTRIDE, int MODE>
__global__ __launch_bounds__(256, 3) void gemm_ep(
    const bf16* __restrict__ A, const bf16* __restrict__ W,
    const float* __restrict__ bias, const float* __restrict__ resid,
    void* __restrict__ outp)
{
    const int tid = threadIdx.x, wave = tid >> 6, lane = tid & 63;
    const int llo = lane & 15, quad = lane >> 4;
    const int tm = blockIdx.x * 64;
    const int tn = blockIdx.y * 64;

    __shared__ __align__(16) bf16 Sa[64 * 200];
    __shared__ __align__(16) bf16 Sb[64 * 200];

    f32x4 acc[4];
#pragma unroll
    for (int nt = 0; nt < 4; ++nt)
#pragma unroll
        for (int r = 0; r < 4; ++r) acc[nt][r] = 0.f;

    constexpr int NCH = (KPAD + 191) / 192;
#pragma unroll
    for (int c = 0; c < NCH; ++c) {
        const int koff = c * 192;
        const bool full = (koff + 192 <= KPAD);
        if (c) __syncthreads();
        if (full) {
            stage_tile<192, KPAD>(A + (long)tm * KPAD + koff, Sa, tid);
            stage_tile<192, KPAD>(W + (long)tn * KPAD + koff, Sb, tid);
        } else {
            stage_tile<160, KPAD>(A + (long)tm * KPAD + koff, Sa, tid);
            stage_tile<160, KPAD>(W + (long)tn * KPAD + koff, Sb, tid);
        }
        __syncthreads();
        const int nkt = full ? 6 : 5;
        for (int kt = 0; kt < nkt; ++kt) {
            bf16x8 a = ld8(Sa + (wave * 16 + llo) * 200 + kt * 32 + quad * 8);
#pragma unroll
            for (int nt = 0; nt < 4; ++nt) {
                bf16x8 b = ld8(Sb + (nt * 16 + llo) * 200 + kt * 32 + quad * 8);
                acc[nt] = MFMA16(a, b, acc[nt]);
            }
        }
    }

#pragma unroll
    for (int nt = 0; nt < 4; ++nt)
#pragma unroll
        for (int r = 0; r < 4; ++r) {
            int m = tm + wave * 16 + quad * 4 + r;
            int n = tn + nt * 16 + llo;
            if (n >= NREAL) continue;
            float v = acc[nt][r] + bias[n];
            if (MODE == 2) {
                ((float*)outp)[(long)m * OSTRIDE + n] = v + resid[(long)m * 180 + n];
            } else {
                float gel = 0.5f * v * (1.f + erff(v * 0.7071067811865475f));
                ((bf16*)outp)[(long)m * OSTRIDE + n] = (bf16)gel;
            }
        }
}

// ---------------------------------------------------------------------------
extern "C" void kernel_launch(void* const* d_in, const int* in_sizes, int n_in,
                              void* d_out, int out_size, void* d_ws, size_t ws_size,
                              hipStream_t stream) {
    const float* x      = (const float*)d_in[0];
    const float* y      = (const float*)d_in[1];
    const float* n1g    = (const float*)d_in[2];
    const float* n1b    = (const float*)d_in[3];
    const float* kv_w   = (const float*)d_in[4];
    const float* kv_b   = (const float*)d_in[5];
    const float* q_w    = (const float*)d_in[6];
    const float* q_b    = (const float*)d_in[7];
    const float* rpb    = (const float*)d_in[8];
    const float* proj_w = (const float*)d_in[9];
    const float* proj_b = (const float*)d_in[10];
    const float* n2g    = (const float*)d_in[11];
    const float* n2b    = (const float*)d_in[12];
    const float* fc1_w  = (const float*)d_in[13];
    const float* fc1_b  = (const float*)d_in[14];
    const float* fc2_w  = (const float*)d_in[15];
    const float* fc2_b  = (const float*)d_in[16];
    const int*   rpi    = (const int*)d_in[17];

    char* ws = (char*)d_ws;
    bf16* xn    = (bf16*)(ws + 0);          // [32768][192] = xn + yn
    bf16* yn    = (bf16*)(ws + 6291456);
    bf16* qbuf  = (bf16*)(ws + 12582912);   // [16384][192]
    bf16* kvbuf = (bf16*)(ws + 18874368);   // [16384][384]
    bf16* obuf  = (bf16*)(ws + 31457280);   // [16384][192]
    float* xo   = (float*)(ws + 37748736);  // [16384][180] fp32
    bf16* biast = (bf16*)(ws + 49545216);   // [6][256][576]
    bf16* wkv   = (bf16*)(ws + 51314688);
    bf16* wq    = (bf16*)(ws + 51462144);
    bf16* wproj = (bf16*)(ws + 51560448);
    bf16* wfc1  = (bf16*)(ws + 51658752);
    bf16* wfc2  = (bf16*)(ws + 51953664);
    bf16* hmid  = (bf16*)(ws + 6291456);    // reuse yn/qbuf/kvbuf (dead post-attn)
    bf16* xn2   = xn;                       // xn dead after gemm_kvq

    prep_kernel<<<5440, 256, 0, stream>>>(kv_w, q_w, proj_w, fc1_w, fc2_w, rpb, rpi,
                                          wkv, wq, wproj, wfc1, wfc2, biast);
    ln_kernel<<<8192, 256, 0, stream>>>(x, y, n1g, n1b, xn);
    gemm_kvq<<<dim3(256, 9), 256, 0, stream>>>(xn, yn, wkv, wq, kv_b, q_b, kvbuf, qbuf);
    attn_kernel<<<768, 512, 0, stream>>>(qbuf, kvbuf, biast, obuf);
    gemm_projln<<<256, 256, 0, stream>>>(obuf, wproj, proj_b, x, n2g, n2b, xo, xn2);
    gemm_ep<192, 720, 736, 3><<<dim3(256, 12), 256, 0, stream>>>(xn2, wfc1, fc1_b, nullptr, hmid);
    gemm_ep<736, 180, 180, 2><<<dim3(256, 3), 256, 0, stream>>>(hmid, wfc2, fc2_b, xo, (float*)d_out);
}

// Round 9
// 211.874 us; speedup vs baseline: 1.3462x; 1.0456x over previous
//
#include <hip/hip_runtime.h>

typedef __bf16 bf16;
typedef __bf16 bf16x8 __attribute__((ext_vector_type(8)));
typedef __bf16 bf16x4 __attribute__((ext_vector_type(4)));
typedef __bf16 bf16x2 __attribute__((ext_vector_type(2)));
typedef float f32x4 __attribute__((ext_vector_type(4)));

static __device__ __forceinline__ bf16x8 ld8(const bf16* p) {
    return *reinterpret_cast<const bf16x8*>(p);
}
static __device__ __forceinline__ bf16x4 ld4(const bf16* p) {
    return *reinterpret_cast<const bf16x4*>(p);
}
static __device__ __forceinline__ bf16x8 ld8_b32(const bf16* p) {
    bf16x8 v;
#pragma unroll
    for (int i = 0; i < 4; ++i) {
        bf16x2 t = *reinterpret_cast<const bf16x2*>(p + i * 2);
        v[i * 2] = t[0]; v[i * 2 + 1] = t[1];
    }
    return v;
}
static __device__ __forceinline__ bf16x8 zero8() {
    bf16x8 v;
#pragma unroll
    for (int i = 0; i < 8; ++i) v[i] = (bf16)0.f;
    return v;
}

#define MFMA16(a, b, c) __builtin_amdgcn_mfma_f32_16x16x32_bf16((a), (b), (c), 0, 0, 0)

// Stage a 64-row x BK tile (global row stride KPAD) into LDS (row stride 200).
template <int BK, int KPAD>
static __device__ __forceinline__ void stage_tile(const bf16* __restrict__ g,
                                                  bf16* __restrict__ lds, int tid) {
    constexpr int CPR = BK / 8;
    constexpr int NP = 64 * CPR / 256;
#pragma unroll
    for (int p = 0; p < NP; ++p) {
        int idx = p * 256 + tid;
        int row = idx / CPR, cg = idx % CPR;
        bf16x8 v = ld8(g + (long)row * KPAD + cg * 8);
        *reinterpret_cast<bf16x8*>(lds + row * 200 + cg * 8) = v;
    }
}
// Same split into load-to-regs / store-from-regs for prefetch pipelines.
template <int BK, int KPAD>
static __device__ __forceinline__ void load_chunk(const bf16* __restrict__ g,
                                                  bf16x8* r, int tid) {
    constexpr int CPR = BK / 8;
    constexpr int NP = 64 * CPR / 256;
#pragma unroll
    for (int p = 0; p < NP; ++p) {
        int idx = p * 256 + tid;
        int row = idx / CPR, cg = idx % CPR;
        r[p] = ld8(g + (long)row * KPAD + cg * 8);
    }
}
template <int BK>
static __device__ __forceinline__ void store_chunk(bf16* __restrict__ lds,
                                                   const bf16x8* r, int tid) {
    constexpr int CPR = BK / 8;
    constexpr int NP = 64 * CPR / 256;
#pragma unroll
    for (int p = 0; p < NP; ++p) {
        int idx = p * 256 + tid;
        int row = idx / CPR, cg = idx % CPR;
        *reinterpret_cast<bf16x8*>(lds + row * 200 + cg * 8) = r[p];
    }
}

// ---------------------------------------------------------------------------
// prep: weights fp32->bf16 with pad/scatter; bias table in COALESCED layout:
//   biast[h][qg(16)][kg(36)][lane(64)][4] =
//       rpb[rpi[(qg*16 + (lane&15))*576 + kg*16 + (lane>>4)*4 + r]][h]
// so attn's per-fragment bias load is one coalesced ld4 per wave.
// ---------------------------------------------------------------------------
__global__ __launch_bounds__(256) void prep_kernel(
    const float* __restrict__ kv_w, const float* __restrict__ q_w,
    const float* __restrict__ proj_w, const float* __restrict__ fc1_w,
    const float* __restrict__ fc2_w, const float* __restrict__ rpb,
    const int* __restrict__ rpi,
    bf16* __restrict__ wkv, bf16* __restrict__ wq, bf16* __restrict__ wproj,
    bf16* __restrict__ wfc1, bf16* __restrict__ wfc2, bf16* __restrict__ biast)
{
    int i = blockIdx.x * 256 + threadIdx.x;
    if (i < 73728) {                       // wkv
        int n = i / 192, k = i % 192;
        float v = (n < 360 && k < 180) ? kv_w[n * 180 + k] : 0.f;
        wkv[i] = (bf16)v;
    } else if (i < 122880) {               // wq
        int j = i - 73728; int n = j / 192, k = j % 192;
        float v = (n < 180 && k < 180) ? q_w[n * 180 + k] : 0.f;
        wq[j] = (bf16)v;
    } else if (i < 172032) {               // wproj (head-padded K)
        int j = i - 122880; int n = j / 192, k = j % 192;
        int hh = k >> 5, d = k & 31;
        float v = (n < 180 && d < 30) ? proj_w[n * 180 + hh * 30 + d] : 0.f;
        wproj[j] = (bf16)v;
    } else if (i < 319488) {               // wfc1
        int j = i - 172032; int n = j / 192, k = j % 192;
        float v = (n < 720 && k < 180) ? fc1_w[n * 180 + k] : 0.f;
        wfc1[j] = (bf16)v;
    } else if (i < 507904) {               // wfc2
        int j = i - 319488; int n = j / 736, k = j % 736;
        float v = (n < 180 && k < 720) ? fc2_w[n * 720 + k] : 0.f;
        wfc2[j] = (bf16)v;
    } else if (i < 1392640) {              // bias table, frag-coalesced layout
        int t = i - 507904;                // 0..884735
        int r = t & 3;
        int lane = (t >> 2) & 63;
        int tmp2 = t >> 8;                 // 0..3455
        int kg = tmp2 % 36;
        int tmp3 = tmp2 / 36;              // 0..95
        int qg = tmp3 & 15;
        int h = tmp3 >> 4;
        int q = qg * 16 + (lane & 15);
        int key = kg * 16 + ((lane >> 4) << 2) + r;
        biast[t] = (bf16)rpb[rpi[q * 576 + key] * 6 + h];
    }
}

// ---------------------------------------------------------------------------
// LayerNorm: one wave per row of 180 fp32 -> bf16 [row][192] (tail zeroed).
// ---------------------------------------------------------------------------
__global__ __launch_bounds__(256) void ln_kernel(
    const float* __restrict__ srcA, const float* __restrict__ srcB,
    const float* __restrict__ g, const float* __restrict__ b,
    bf16* __restrict__ dst)
{
    int wave = threadIdx.x >> 6, lane = threadIdx.x & 63;
    int row = blockIdx.x * 4 + wave;
    const float* sp = (row < 16384) ? (srcA + row * 180) : (srcB + (row - 16384) * 180);
    float v0 = sp[lane];
    float v1 = sp[lane + 64];
    float v2 = (lane < 52) ? sp[lane + 128] : 0.f;
    float s = v0 + v1 + v2;
    float sq = v0 * v0 + v1 * v1 + v2 * v2;
#pragma unroll
    for (int m = 32; m >= 1; m >>= 1) {
        s += __shfl_xor(s, m);
        sq += __shfl_xor(sq, m);
    }
    float mean = s * (1.f / 180.f);
    float var = sq * (1.f / 180.f) - mean * mean;
    float rs = rsqrtf(var + 1e-5f);
    bf16* dp = dst + (long)row * 192;
    dp[lane] = (bf16)((v0 - mean) * rs * g[lane] + b[lane]);
    dp[lane + 64] = (bf16)((v1 - mean) * rs * g[lane + 64] + b[lane + 64]);
    float o2 = (lane < 52) ? ((v2 - mean) * rs * g[lane + 128] + b[lane + 128]) : 0.f;
    dp[lane + 128] = (bf16)o2;
}

// ---------------------------------------------------------------------------
// kv+q projection: block = 64 rows x 3 N-groups. A staged once; W tiles
// register-prefetched across subrounds. grid = (256, 3); bz=2 -> q groups.
// ---------------------------------------------------------------------------
__global__ __launch_bounds__(256, 4) void gemm_kvq(
    const bf16* __restrict__ xn, const bf16* __restrict__ yn,
    const bf16* __restrict__ wkv, const bf16* __restrict__ wq,
    const float* __restrict__ kv_b, const float* __restrict__ q_b,
    bf16* __restrict__ kvbuf, bf16* __restrict__ qbuf)
{
    const int tid = threadIdx.x, wave = tid >> 6, lane = tid & 63;
    const int llo = lane & 15, quad = lane >> 4;
    const int bz = blockIdx.y;
    const bool isq = (bz == 2);
    const bf16* A = isq ? yn : xn;
    const bf16* Wbase = isq ? wq : (wkv + (long)bz * 3 * 64 * 192);
    const int tm = blockIdx.x * 64;

    __shared__ __align__(16) bf16 Sa[64 * 200];
    __shared__ __align__(16) bf16 Sb[64 * 200];

    stage_tile<192, 192>(A + (long)tm * 192, Sa, tid);
    bf16x8 wreg[6];
    load_chunk<192, 192>(Wbase, wreg, tid);

    for (int s = 0; s < 3; ++s) {
        if (s) __syncthreads();            // protect prior Sb reads
        store_chunk<192>(Sb, wreg, tid);
        __syncthreads();                   // Sa (first iter) + Sb ready
        if (s < 2) load_chunk<192, 192>(Wbase + (long)(s + 1) * 64 * 192, wreg, tid);

        f32x4 acc[4];
#pragma unroll
        for (int nt = 0; nt < 4; ++nt)
#pragma unroll
            for (int r = 0; r < 4; ++r) acc[nt][r] = 0.f;
#pragma unroll
        for (int kt = 0; kt < 6; ++kt) {
            bf16x8 a = ld8(Sa + (wave * 16 + llo) * 200 + kt * 32 + quad * 8);
#pragma unroll
            for (int nt = 0; nt < 4; ++nt) {
                bf16x8 b = ld8(Sb + (nt * 16 + llo) * 200 + kt * 32 + quad * 8);
                acc[nt] = MFMA16(a, b, acc[nt]);
            }
        }

        const int g = bz * 3 + s;
#pragma unroll
        for (int nt = 0; nt < 4; ++nt)
#pragma unroll
            for (int r = 0; r < 4; ++r) {
                int m = tm + wave * 16 + quad * 4 + r;
                int n = g * 64 + nt * 16 + llo;
                if (!isq) {
                    if (n < 360) {
                        float v = acc[nt][r] + kv_b[n];
                        int nn = n % 180;
                        int col = (n / 180) * 192 + (nn / 30) * 32 + (nn % 30);
                        kvbuf[(long)m * 384 + col] = (bf16)v;
                    }
                } else {
                    int nq = n - 384;
                    if (nq < 180) {
                        float v = (acc[nt][r] + q_b[nq]) * 0.18257418583505537f;
                        int col = (nq / 30) * 32 + (nq % 30);
                        qbuf[(long)m * 192 + col] = (bf16)v;
                    }
                }
            }
    }
}

// ---------------------------------------------------------------------------
// Attention v7: double-buffered Kc/Vt (ONE barrier per chunk) + coalesced
// bias table. Transposed-S formulation as before.
// ---------------------------------------------------------------------------
__global__ __launch_bounds__(512, 6) void attn_kernel(
    const bf16* __restrict__ qbuf,   // [16384][192] head-padded, pre-scaled
    const bf16* __restrict__ kvbuf,  // [16384][384] K at +0, V at +192
    const bf16* __restrict__ biast,  // [6][16][36][64][4] frag-coalesced
    bf16* __restrict__ obuf)         // [16384][192] head-padded
{
    const int qhalf = blockIdx.x & 1;
    const int head = (blockIdx.x >> 1) % 6;
    const int win = blockIdx.x / 12;
    const int bb = win / 16, wi = (win % 16) / 4, wj = win % 4;
    const int tid = threadIdx.x;
    const int wave = tid >> 6, lane = tid & 63;
    const int llo = lane & 15, quad = lane >> 4;
    const int qbase = qhalf * 128 + wave * 16;
    const int qg = qhalf * 8 + wave;

    __shared__ bf16 Kc[2][64][40];
    __shared__ bf16 Vt[2][32][74];
    __shared__ bf16 Ps[8][16][72];

    const int u = tid & 255;
    const int tloc = u >> 2, dq = u & 3;
    const bool isV = tid >= 256;
    int aa = tloc / 24, w0 = tloc % 24;

    const int q0 = qbase + llo;
    const int gr_q = bb * 4096 + (wi * 16 + (q0 >> 4)) * 64 + (wj * 16 + (q0 & 15));
    const bf16x8 qf = ld8(qbuf + (long)gr_q * 192 + head * 32 + quad * 8);
    const bf16* bbase = biast + ((long)(head * 16 + qg) * 36) * 256 + lane * 4;

    // chunk 0: load + store into buffer 0
    {
        int gy = wi * 16 + aa - 4, gx = wj * 16 + w0 - 4;
        bf16x8 st = zero8();
        if ((unsigned)gy < 64u && (unsigned)gx < 64u) {
            long gr = (long)(bb * 4096 + gy * 64 + gx) * 384;
            st = ld8(kvbuf + gr + (isV ? 192 : 0) + head * 32 + dq * 8);
        }
        if (!isV) {
            *reinterpret_cast<bf16x8*>(&Kc[0][tloc][dq * 8]) = st;
        } else {
#pragma unroll
            for (int j = 0; j < 8; ++j) Vt[0][dq * 8 + j][tloc] = st[j];
        }
    }
    __syncthreads();

    f32x4 o[2];
    float m_run = -1e30f, l_run = 0.f;
#pragma unroll
    for (int n2 = 0; n2 < 2; ++n2)
#pragma unroll
        for (int r = 0; r < 4; ++r) o[n2][r] = 0.f;

    for (int c = 0; c < 9; ++c) {
        const int cur = c & 1;

        // issue chunk c+1's global loads immediately
        bf16x8 stage;
        if (c < 8) {
            w0 += 16; aa += 2;
            if (w0 >= 24) { w0 -= 24; ++aa; }
            int gy = wi * 16 + aa - 4, gx = wj * 16 + w0 - 4;
            stage = zero8();
            if ((unsigned)gy < 64u && (unsigned)gx < 64u) {
                long gr = (long)(bb * 4096 + gy * 64 + gx) * 384;
                stage = ld8(kvbuf + gr + (isV ? 192 : 0) + head * 32 + dq * 8);
            }
        }

        // ---- S^T = K·Q^T ----
        f32x4 s[4];
#pragma unroll
        for (int kt = 0; kt < 4; ++kt) {
            bf16x8 kf = ld8(&Kc[cur][kt * 16 + llo][quad * 8]);
            f32x4 zc;
            zc[0] = 0.f; zc[1] = 0.f; zc[2] = 0.f; zc[3] = 0.f;
            s[kt] = MFMA16(kf, qf, zc);
        }

        // ---- + bias (coalesced ld4 per fragment) ----
#pragma unroll
        for (int kt = 0; kt < 4; ++kt) {
            bf16x4 bv = ld4(bbase + (c * 4 + kt) * 256);
#pragma unroll
            for (int r = 0; r < 4; ++r) s[kt][r] += (float)bv[r];
        }

        // ---- online softmax ----
        float mx = s[0][0];
#pragma unroll
        for (int kt = 0; kt < 4; ++kt)
#pragma unroll
            for (int r = 0; r < 4; ++r) mx = fmaxf(mx, s[kt][r]);
        mx = fmaxf(mx, __shfl_xor(mx, 16));
        mx = fmaxf(mx, __shfl_xor(mx, 32));
        float m_new = fmaxf(m_run, mx);
        float alpha = __expf(m_run - m_new);
        float ls = 0.f;
#pragma unroll
        for (int kt = 0; kt < 4; ++kt)
#pragma unroll
            for (int r = 0; r < 4; ++r) {
                float p = __expf(s[kt][r] - m_new);
                s[kt][r] = p;
                ls += p;
            }
        ls += __shfl_xor(ls, 16);
        ls += __shfl_xor(ls, 32);
        l_run = l_run * alpha + ls;
        m_run = m_new;

#pragma unroll
        for (int r = 0; r < 4; ++r) {
            float a = __shfl(alpha, quad * 4 + r);
            o[0][r] *= a;
            o[1][r] *= a;
        }

        // ---- P -> LDS (wave-private) ----
#pragma unroll
        for (int kt = 0; kt < 4; ++kt) {
            bf16x4 pv;
#pragma unroll
            for (int r = 0; r < 4; ++r) pv[r] = (bf16)s[kt][r];
            *reinterpret_cast<bf16x4*>(&Ps[wave][llo][kt * 16 + quad * 4]) = pv;
        }

        // ---- O += P·V ----
#pragma unroll
        for (int kt2 = 0; kt2 < 2; ++kt2) {
            bf16x8 pa = ld8(&Ps[wave][llo][kt2 * 32 + quad * 8]);
#pragma unroll
            for (int n2 = 0; n2 < 2; ++n2) {
                bf16x8 vb = ld8_b32(&Vt[cur][n2 * 16 + llo][kt2 * 32 + quad * 8]);
                o[n2] = MFMA16(pa, vb, o[n2]);
            }
        }

        // ---- store chunk c+1 into other buffer, single barrier ----
        if (c < 8) {
            if (!isV) {
                *reinterpret_cast<bf16x8*>(&Kc[1 - cur][tloc][dq * 8]) = stage;
            } else {
#pragma unroll
                for (int j = 0; j < 8; ++j) Vt[1 - cur][dq * 8 + j][tloc] = stage[j];
            }
            __syncthreads();
        }
    }

    float linv = 1.f / l_run;
#pragma unroll
    for (int r = 0; r < 4; ++r) {
        float li = __shfl(linv, quad * 4 + r);
        int q = qbase + quad * 4 + r;
        int gr = bb * 4096 + (wi * 16 + (q >> 4)) * 64 + (wj * 16 + (q & 15));
#pragma unroll
        for (int n2 = 0; n2 < 2; ++n2)
            obuf[(long)gr * 192 + head * 32 + n2 * 16 + llo] = (bf16)(o[n2][r] * li);
    }
}

// ---------------------------------------------------------------------------
// Fused proj + bias + residual + LN2; W tiles register-prefetched.
// ---------------------------------------------------------------------------
__global__ __launch_bounds__(256, 3) void gemm_projln(
    const bf16* __restrict__ obuf, const bf16* __restrict__ wproj,
    const float* __restrict__ proj_b, const float* __restrict__ x,
    const float* __restrict__ g, const float* __restrict__ bln,
    float* __restrict__ xo, bf16* __restrict__ xn2)
{
    const int tid = threadIdx.x, wave = tid >> 6, lane = tid & 63;
    const int llo = lane & 15, quad = lane >> 4;
    const int mbase = blockIdx.x * 64;

    __shared__ __align__(16) bf16 Sa[64 * 200];
    __shared__ __align__(16) bf16 Sb[64 * 200];
    stage_tile<192, 192>(obuf + (long)mbase * 192, Sa, tid);
    bf16x8 wreg[6];
    load_chunk<192, 192>(wproj, wreg, tid);

    f32x4 acc[12];
#pragma unroll
    for (int nt = 0; nt < 12; ++nt)
#pragma unroll
        for (int r = 0; r < 4; ++r) acc[nt][r] = 0.f;

    for (int nc = 0; nc < 3; ++nc) {
        if (nc) __syncthreads();
        store_chunk<192>(Sb, wreg, tid);
        __syncthreads();
        if (nc < 2) load_chunk<192, 192>(wproj + (long)(nc + 1) * 64 * 192, wreg, tid);
#pragma unroll
        for (int kt = 0; kt < 6; ++kt) {
            bf16x8 a = ld8(Sa + (wave * 16 + llo) * 200 + kt * 32 + quad * 8);
#pragma unroll
            for (int nt = 0; nt < 4; ++nt) {
                bf16x8 b = ld8(Sb + (nt * 16 + llo) * 200 + kt * 32 + quad * 8);
                acc[nc * 4 + nt] = MFMA16(a, b, acc[nc * 4 + nt]);
            }
        }
    }

#pragma unroll
    for (int r = 0; r < 4; ++r) {
        int m = mbase + wave * 16 + quad * 4 + r;
        float v[12];
        float sum = 0.f, sq = 0.f;
#pragma unroll
        for (int nt = 0; nt < 12; ++nt) {
            int n = nt * 16 + llo;
            float val = 0.f;
            if (n < 180) val = acc[nt][r] + proj_b[n] + x[(long)m * 180 + n];
            v[nt] = val;
            sum += val; sq += val * val;
        }
#pragma unroll
        for (int msk = 1; msk <= 8; msk <<= 1) {
            sum += __shfl_xor(sum, msk);
            sq  += __shfl_xor(sq, msk);
        }
        float mean = sum * (1.f / 180.f);
        float var = sq * (1.f / 180.f) - mean * mean;
        float rs = rsqrtf(var + 1e-5f);
#pragma unroll
        for (int nt = 0; nt < 12; ++nt) {
            int n = nt * 16 + llo;
            if (n < 180) {
                xo[(long)m * 180 + n] = v[nt];
                xn2[(long)m * 192 + n] = (bf16)((v[nt] - mean) * rs * g[n] + bln[n]);
            } else {
                xn2[(long)m * 192 + n] = (bf16)0.f;
            }
        }
    }
}

// ---------------------------------------------------------------------------
// fc1: block = 64 rows x 3 N-groups (grid (256,4)); A staged once,
// W register-prefetched. out = gelu(v) bf16 -> hmid[.][736].
// ---------------------------------------------------------------------------
__global__ __launch_bounds__(256, 4) void gemm_fc1(
    const bf16* __restrict__ A, const bf16* __restrict__ W,
    const float* __restrict__ bias, bf16* __restrict__ outp)
{
    const int tid = threadIdx.x, wave = tid >> 6, lane = tid & 63;
    const int llo = lane & 15, quad = lane >> 4;
    const int tm = blockIdx.x * 64;
    const int bz = blockIdx.y;
    const bf16* Wbase = W + (long)bz * 3 * 64 * 192;

    __shared__ __align__(16) bf16 Sa[64 * 200];
    __shared__ __align__(16) bf16 Sb[64 * 200];
    stage_tile<192, 192>(A + (long)tm * 192, Sa, tid);
    bf16x8 wreg[6];
    load_chunk<192, 192>(Wbase, wreg, tid);

    for (int s = 0; s < 3; ++s) {
        if (s) __syncthreads();
        store_chunk<192>(Sb, wreg, tid);
        __syncthreads();
        if (s < 2) load_chunk<192, 192>(Wbase + (long)(s + 1) * 64 * 192, wreg, tid);

        f32x4 acc[4];
#pragma unroll
        for (int nt = 0; nt < 4; ++nt)
#pragma unroll
            for (int r = 0; r < 4; ++r) acc[nt][r] = 0.f;
#pragma unroll
        for (int kt = 0; kt < 6; ++kt) {
            bf16x8 a = ld8(Sa + (wave * 16 + llo) * 200 + kt * 32 + quad * 8);
#pragma unroll
            for (int nt = 0; nt < 4; ++nt) {
                bf16x8 b = ld8(Sb + (nt * 16 + llo) * 200 + kt * 32 + quad * 8);
                acc[nt] = MFMA16(a, b, acc[nt]);
            }
        }

        const int nb = (bz * 3 + s) * 64;
#pragma unroll
        for (int nt = 0; nt < 4; ++nt)
#pragma unroll
            for (int r = 0; r < 4; ++r) {
                int m = tm + wave * 16 + quad * 4 + r;
                int n = nb + nt * 16 + llo;
                if (n >= 720) continue;
                float v = acc[nt][r] + bias[n];
                float gel = 0.5f * v * (1.f + erff(v * 0.7071067811865475f));
                outp[(long)m * 736 + n] = (bf16)gel;
            }
    }
}

// ---------------------------------------------------------------------------
// fc2: 64x64 tile, K=736 in chunks 192/192/192/160 with register prefetch
// of the next chunk (A and W) during current compute. fp32 out + resid.
// ---------------------------------------------------------------------------
__global__ __launch_bounds__(256, 4) void gemm_fc2(
    const bf16* __restrict__ A, const bf16* __restrict__ W,
    const float* __restrict__ bias, const float* __restrict__ resid,
    float* __restrict__ outp)
{
    const int tid = threadIdx.x, wave = tid >> 6, lane = tid & 63;
    const int llo = lane & 15, quad = lane >> 4;
    const int tm = blockIdx.x * 64;
    const int tn = blockIdx.y * 64;

    __shared__ __align__(16) bf16 Sa[64 * 200];
    __shared__ __align__(16) bf16 Sb[64 * 200];

    const bf16* Ap = A + (long)tm * 736;
    const bf16* Wp = W + (long)tn * 736;

    bf16x8 ar[6], wr[6];
    load_chunk<192, 736>(Ap, ar, tid);
    load_chunk<192, 736>(Wp, wr, tid);

    f32x4 acc[4];
#pragma unroll
    for (int nt = 0; nt < 4; ++nt)
#pragma unroll
        for (int r = 0; r < 4; ++r) acc[nt][r] = 0.f;

#pragma unroll
    for (int c = 0; c < 4; ++c) {
        if (c) __syncthreads();
        if (c < 3) { store_chunk<192>(Sa, ar, tid); store_chunk<192>(Sb, wr, tid); }
        else       { store_chunk<160>(Sa, ar, tid); store_chunk<160>(Sb, wr, tid); }
        __syncthreads();
        if (c < 2) {
            load_chunk<192, 736>(Ap + (c + 1) * 192, ar, tid);
            load_chunk<192, 736>(Wp + (c + 1) * 192, wr, tid);
        } else if (c == 2) {
            load_chunk<160, 736>(Ap + 576, ar, tid);
            load_chunk<160, 736>(Wp + 576, wr, tid);
        }
        const int nkt = (c == 3) ? 5 : 6;
        for (int kt = 0; kt < nkt; ++kt) {
            bf16x8 a = ld8(Sa + (wave * 16 + llo) * 200 + kt * 32 + quad * 8);
#pragma unroll
            for (int nt = 0; nt < 4; ++nt) {
                bf16x8 b = ld8(Sb + (nt * 16 + llo) * 200 + kt * 32 + quad * 8);
                acc[nt] = MFMA16(a, b, acc[nt]);
            }
        }
    }

#pragma unroll
    for (int nt = 0; nt < 4; ++nt)
#pragma unroll
        for (int r = 0; r < 4; ++r) {
            int m = tm + wave * 16 + quad * 4 + r;
            int n = tn + nt * 16 + llo;
            if (n >= 180) continue;
            float v = acc[nt][r] + bias[n];
            outp[(long)m * 180 + n] = v + resid[(long)m * 180 + n];
        }
}

// ---------------------------------------------------------------------------
extern "C" void kernel_launch(void* const* d_in, const int* in_sizes, int n_in,
                              void* d_out, int out_size, void* d_ws, size_t ws_size,
                              hipStream_t stream) {
    const float* x      = (const float*)d_in[0];
    const float* y      = (const float*)d_in[1];
    const float* n1g    = (const float*)d_in[2];
    const float* n1b    = (const float*)d_in[3];
    const float* kv_w   = (const float*)d_in[4];
    const float* kv_b   = (const float*)d_in[5];
    const float* q_w    = (const float*)d_in[6];
    const float* q_b    = (const float*)d_in[7];
    const float* rpb    = (const float*)d_in[8];
    const float* proj_w = (const float*)d_in[9];
    const float* proj_b = (const float*)d_in[10];
    const float* n2g    = (const float*)d_in[11];
    const float* n2b    = (const float*)d_in[12];
    const float* fc1_w  = (const float*)d_in[13];
    const float* fc1_b  = (const float*)d_in[14];
    const float* fc2_w  = (const float*)d_in[15];
    const float* fc2_b  = (const float*)d_in[16];
    const int*   rpi    = (const int*)d_in[17];

    char* ws = (char*)d_ws;
    bf16* xn    = (bf16*)(ws + 0);          // [32768][192] = xn + yn
    bf16* yn    = (bf16*)(ws + 6291456);
    bf16* qbuf  = (bf16*)(ws + 12582912);   // [16384][192]
    bf16* kvbuf = (bf16*)(ws + 18874368);   // [16384][384]
    bf16* obuf  = (bf16*)(ws + 31457280);   // [16384][192]
    float* xo   = (float*)(ws + 37748736);  // [16384][180] fp32
    bf16* biast = (bf16*)(ws + 49545216);   // [6][16][36][64][4]
    bf16* wkv   = (bf16*)(ws + 51314688);
    bf16* wq    = (bf16*)(ws + 51462144);
    bf16* wproj = (bf16*)(ws + 51560448);
    bf16* wfc1  = (bf16*)(ws + 51658752);
    bf16* wfc2  = (bf16*)(ws + 51953664);
    bf16* hmid  = (bf16*)(ws + 6291456);    // reuse yn/qbuf/kvbuf (dead post-attn)
    bf16* xn2   = xn;                       // xn dead after gemm_kvq

    prep_kernel<<<5440, 256, 0, stream>>>(kv_w, q_w, proj_w, fc1_w, fc2_w, rpb, rpi,
                                          wkv, wq, wproj, wfc1, wfc2, biast);
    ln_kernel<<<8192, 256, 0, stream>>>(x, y, n1g, n1b, xn);
    gemm_kvq<<<dim3(256, 3), 256, 0, stream>>>(xn, yn, wkv, wq, kv_b, q_b, kvbuf, qbuf);
    attn_kernel<<<768, 512, 0, stream>>>(qbuf, kvbuf, biast, obuf);
    gemm_projln<<<256, 256, 0, stream>>>(obuf, wproj, proj_b, x, n2g, n2b, xo, xn2);
    gemm_fc1<<<dim3(256, 4), 256, 0, stream>>>(xn2, wfc1, fc1_b, hmid);
    gemm_fc2<<<dim3(256, 3), 256, 0, stream>>>(hmid, wfc2, fc2_b, xo, (float*)d_out);
}

// Round 10
// 201.640 us; speedup vs baseline: 1.4145x; 1.0508x over previous
//
#include <hip/hip_runtime.h>

typedef __bf16 bf16;
typedef __bf16 bf16x8 __attribute__((ext_vector_type(8)));
typedef __bf16 bf16x4 __attribute__((ext_vector_type(4)));
typedef __bf16 bf16x2 __attribute__((ext_vector_type(2)));
typedef float f32x4 __attribute__((ext_vector_type(4)));

static __device__ __forceinline__ bf16x8 ld8(const bf16* p) {
    return *reinterpret_cast<const bf16x8*>(p);
}
static __device__ __forceinline__ bf16x4 ld4(const bf16* p) {
    return *reinterpret_cast<const bf16x4*>(p);
}
static __device__ __forceinline__ bf16x8 ld8_b32(const bf16* p) {
    bf16x8 v;
#pragma unroll
    for (int i = 0; i < 4; ++i) {
        bf16x2 t = *reinterpret_cast<const bf16x2*>(p + i * 2);
        v[i * 2] = t[0]; v[i * 2 + 1] = t[1];
    }
    return v;
}
static __device__ __forceinline__ bf16x8 zero8() {
    bf16x8 v;
#pragma unroll
    for (int i = 0; i < 8; ++i) v[i] = (bf16)0.f;
    return v;
}

#define MFMA16(a, b, c) __builtin_amdgcn_mfma_f32_16x16x32_bf16((a), (b), (c), 0, 0, 0)

// Generic tile movers. LDS row stride fixed at 200 elems (conflict-free for
// both the b128 staging stores and the fragment ds_read_b128s).
template <int ROWS, int BK, int KPAD, int THREADS>
static __device__ __forceinline__ void load_chunk_g(const bf16* __restrict__ g,
                                                    bf16x8* r, int tid) {
    constexpr int TOT = ROWS * BK / 8;
    constexpr int NP = (TOT + THREADS - 1) / THREADS;
#pragma unroll
    for (int p = 0; p < NP; ++p) {
        int idx = p * THREADS + tid;
        if ((TOT % THREADS) == 0 || idx < TOT) {
            int row = idx / (BK / 8), cg = idx % (BK / 8);
            r[p] = ld8(g + (long)row * KPAD + cg * 8);
        }
    }
}
template <int ROWS, int BK, int THREADS>
static __device__ __forceinline__ void store_chunk_l(bf16* __restrict__ lds,
                                                     const bf16x8* r, int tid) {
    constexpr int TOT = ROWS * BK / 8;
    constexpr int NP = (TOT + THREADS - 1) / THREADS;
#pragma unroll
    for (int p = 0; p < NP; ++p) {
        int idx = p * THREADS + tid;
        if ((TOT % THREADS) == 0 || idx < TOT) {
            int row = idx / (BK / 8), cg = idx % (BK / 8);
            *reinterpret_cast<bf16x8*>(lds + row * 200 + cg * 8) = r[p];
        }
    }
}
template <int ROWS, int BK, int KPAD, int THREADS>
static __device__ __forceinline__ void stage_tile(const bf16* __restrict__ g,
                                                  bf16* __restrict__ lds, int tid) {
    constexpr int TOT = ROWS * BK / 8;
    constexpr int NP = (TOT + THREADS - 1) / THREADS;
#pragma unroll
    for (int p = 0; p < NP; ++p) {
        int idx = p * THREADS + tid;
        if ((TOT % THREADS) == 0 || idx < TOT) {
            int row = idx / (BK / 8), cg = idx % (BK / 8);
            bf16x8 v = ld8(g + (long)row * KPAD + cg * 8);
            *reinterpret_cast<bf16x8*>(lds + row * 200 + cg * 8) = v;
        }
    }
}

// ---------------------------------------------------------------------------
// fused_pre: blocks [0,8192) do LayerNorm of x|y (4 rows/block);
// blocks [8192,13632) do weight conversion + bias-table gather (prep).
//   biast[h][qg(16)][kg(36)][lane(64)][4] coalesced layout (see round 9).
// ---------------------------------------------------------------------------
__global__ __launch_bounds__(256) void fused_pre(
    const float* __restrict__ x, const float* __restrict__ y,
    const float* __restrict__ g, const float* __restrict__ b,
    bf16* __restrict__ dst,
    const float* __restrict__ kv_w, const float* __restrict__ q_w,
    const float* __restrict__ proj_w, const float* __restrict__ fc1_w,
    const float* __restrict__ fc2_w, const float* __restrict__ rpb,
    const int* __restrict__ rpi,
    bf16* __restrict__ wkv, bf16* __restrict__ wq, bf16* __restrict__ wproj,
    bf16* __restrict__ wfc1, bf16* __restrict__ wfc2, bf16* __restrict__ biast)
{
    if (blockIdx.x < 8192) {
        int wave = threadIdx.x >> 6, lane = threadIdx.x & 63;
        int row = blockIdx.x * 4 + wave;
        const float* sp = (row < 16384) ? (x + (long)row * 180)
                                        : (y + (long)(row - 16384) * 180);
        float v0 = sp[lane];
        float v1 = sp[lane + 64];
        float v2 = (lane < 52) ? sp[lane + 128] : 0.f;
        float s = v0 + v1 + v2;
        float sq = v0 * v0 + v1 * v1 + v2 * v2;
#pragma unroll
        for (int m = 32; m >= 1; m >>= 1) {
            s += __shfl_xor(s, m);
            sq += __shfl_xor(sq, m);
        }
        float mean = s * (1.f / 180.f);
        float var = sq * (1.f / 180.f) - mean * mean;
        float rs = rsqrtf(var + 1e-5f);
        bf16* dp = dst + (long)row * 192;
        dp[lane] = (bf16)((v0 - mean) * rs * g[lane] + b[lane]);
        dp[lane + 64] = (bf16)((v1 - mean) * rs * g[lane + 64] + b[lane + 64]);
        float o2 = (lane < 52) ? ((v2 - mean) * rs * g[lane + 128] + b[lane + 128]) : 0.f;
        dp[lane + 128] = (bf16)o2;
        return;
    }
    int i = (blockIdx.x - 8192) * 256 + threadIdx.x;
    if (i < 73728) {                       // wkv
        int n = i / 192, k = i % 192;
        float v = (n < 360 && k < 180) ? kv_w[n * 180 + k] : 0.f;
        wkv[i] = (bf16)v;
    } else if (i < 122880) {               // wq
        int j = i - 73728; int n = j / 192, k = j % 192;
        float v = (n < 180 && k < 180) ? q_w[n * 180 + k] : 0.f;
        wq[j] = (bf16)v;
    } else if (i < 172032) {               // wproj (head-padded K)
        int j = i - 122880; int n = j / 192, k = j % 192;
        int hh = k >> 5, d = k & 31;
        float v = (n < 180 && d < 30) ? proj_w[n * 180 + hh * 30 + d] : 0.f;
        wproj[j] = (bf16)v;
    } else if (i < 319488) {               // wfc1
        int j = i - 172032; int n = j / 192, k = j % 192;
        float v = (n < 720 && k < 180) ? fc1_w[n * 180 + k] : 0.f;
        wfc1[j] = (bf16)v;
    } else if (i < 507904) {               // wfc2
        int j = i - 319488; int n = j / 736, k = j % 736;
        float v = (n < 180 && k < 720) ? fc2_w[n * 720 + k] : 0.f;
        wfc2[j] = (bf16)v;
    } else if (i < 1392640) {              // bias table, frag-coalesced
        int t = i - 507904;
        int r = t & 3;
        int lane = (t >> 2) & 63;
        int tmp2 = t >> 8;
        int kg = tmp2 % 36;
        int tmp3 = tmp2 / 36;
        int qg = tmp3 & 15;
        int h = tmp3 >> 4;
        int q = qg * 16 + (lane & 15);
        int key = kg * 16 + ((lane >> 4) << 2) + r;
        biast[t] = (bf16)rpb[rpi[q * 576 + key] * 6 + h];
    }
}

// ---------------------------------------------------------------------------
// kv+q projection v3: 512 threads, 128-row M-tile, 3 N-subrounds of 64.
// A staged ONCE per 128 rows; W tiles register-prefetched. grid (128, 3).
// ---------------------------------------------------------------------------
__global__ __launch_bounds__(512, 4) void gemm_kvq(
    const bf16* __restrict__ xn, const bf16* __restrict__ yn,
    const bf16* __restrict__ wkv, const bf16* __restrict__ wq,
    const float* __restrict__ kv_b, const float* __restrict__ q_b,
    bf16* __restrict__ kvbuf, bf16* __restrict__ qbuf)
{
    const int tid = threadIdx.x, wave = tid >> 6, lane = tid & 63;
    const int llo = lane & 15, quad = lane >> 4;
    const int bz = blockIdx.y;
    const bool isq = (bz == 2);
    const bf16* A = isq ? yn : xn;
    const bf16* Wbase = isq ? wq : (wkv + (long)bz * 3 * 64 * 192);
    const int tm = blockIdx.x * 128;

    __shared__ __align__(16) bf16 Sa[128 * 200];
    __shared__ __align__(16) bf16 Sb[64 * 200];

    stage_tile<128, 192, 192, 512>(A + (long)tm * 192, Sa, tid);
    bf16x8 wreg[3];
    load_chunk_g<64, 192, 192, 512>(Wbase, wreg, tid);

    for (int s = 0; s < 3; ++s) {
        if (s) __syncthreads();
        store_chunk_l<64, 192, 512>(Sb, wreg, tid);
        __syncthreads();
        if (s < 2) load_chunk_g<64, 192, 192, 512>(Wbase + (long)(s + 1) * 64 * 192, wreg, tid);

        f32x4 acc[4];
#pragma unroll
        for (int nt = 0; nt < 4; ++nt)
#pragma unroll
            for (int r = 0; r < 4; ++r) acc[nt][r] = 0.f;
#pragma unroll
        for (int kt = 0; kt < 6; ++kt) {
            bf16x8 a = ld8(Sa + (wave * 16 + llo) * 200 + kt * 32 + quad * 8);
#pragma unroll
            for (int nt = 0; nt < 4; ++nt) {
                bf16x8 b = ld8(Sb + (nt * 16 + llo) * 200 + kt * 32 + quad * 8);
                acc[nt] = MFMA16(a, b, acc[nt]);
            }
        }

        const int g = bz * 3 + s;
#pragma unroll
        for (int nt = 0; nt < 4; ++nt) {
            int n = g * 64 + nt * 16 + llo;
            if (!isq) {
                if (n < 360) {
                    int nn = n % 180;
                    int col = (n / 180) * 192 + (nn / 30) * 32 + (nn % 30);
                    float bv = kv_b[n];
#pragma unroll
                    for (int r = 0; r < 4; ++r) {
                        int m = tm + wave * 16 + quad * 4 + r;
                        kvbuf[(long)m * 384 + col] = (bf16)(acc[nt][r] + bv);
                    }
                }
            } else {
                int nq = n - 384;
                if (nq < 180) {
                    int col = (nq / 30) * 32 + (nq % 30);
                    float bv = q_b[nq];
#pragma unroll
                    for (int r = 0; r < 4; ++r) {
                        int m = tm + wave * 16 + quad * 4 + r;
                        qbuf[(long)m * 192 + col] =
                            (bf16)((acc[nt][r] + bv) * 0.18257418583505537f);
                    }
                }
            }
        }
    }
}

// ---------------------------------------------------------------------------
// Attention v7 (unchanged): double-buffered Kc/Vt, coalesced bias table,
// transposed-S formulation.
// ---------------------------------------------------------------------------
__global__ __launch_bounds__(512, 6) void attn_kernel(
    const bf16* __restrict__ qbuf, const bf16* __restrict__ kvbuf,
    const bf16* __restrict__ biast, bf16* __restrict__ obuf)
{
    const int qhalf = blockIdx.x & 1;
    const int head = (blockIdx.x >> 1) % 6;
    const int win = blockIdx.x / 12;
    const int bb = win / 16, wi = (win % 16) / 4, wj = win % 4;
    const int tid = threadIdx.x;
    const int wave = tid >> 6, lane = tid & 63;
    const int llo = lane & 15, quad = lane >> 4;
    const int qbase = qhalf * 128 + wave * 16;
    const int qg = qhalf * 8 + wave;

    __shared__ bf16 Kc[2][64][40];
    __shared__ bf16 Vt[2][32][74];
    __shared__ bf16 Ps[8][16][72];

    const int u = tid & 255;
    const int tloc = u >> 2, dq = u & 3;
    const bool isV = tid >= 256;
    int aa = tloc / 24, w0 = tloc % 24;

    const int q0 = qbase + llo;
    const int gr_q = bb * 4096 + (wi * 16 + (q0 >> 4)) * 64 + (wj * 16 + (q0 & 15));
    const bf16x8 qf = ld8(qbuf + (long)gr_q * 192 + head * 32 + quad * 8);
    const bf16* bbase = biast + ((long)(head * 16 + qg) * 36) * 256 + lane * 4;

    {
        int gy = wi * 16 + aa - 4, gx = wj * 16 + w0 - 4;
        bf16x8 st = zero8();
        if ((unsigned)gy < 64u && (unsigned)gx < 64u) {
            long gr = (long)(bb * 4096 + gy * 64 + gx) * 384;
            st = ld8(kvbuf + gr + (isV ? 192 : 0) + head * 32 + dq * 8);
        }
        if (!isV) {
            *reinterpret_cast<bf16x8*>(&Kc[0][tloc][dq * 8]) = st;
        } else {
#pragma unroll
            for (int j = 0; j < 8; ++j) Vt[0][dq * 8 + j][tloc] = st[j];
        }
    }
    __syncthreads();

    f32x4 o[2];
    float m_run = -1e30f, l_run = 0.f;
#pragma unroll
    for (int n2 = 0; n2 < 2; ++n2)
#pragma unroll
        for (int r = 0; r < 4; ++r) o[n2][r] = 0.f;

    for (int c = 0; c < 9; ++c) {
        const int cur = c & 1;

        bf16x8 stage;
        if (c < 8) {
            w0 += 16; aa += 2;
            if (w0 >= 24) { w0 -= 24; ++aa; }
            int gy = wi * 16 + aa - 4, gx = wj * 16 + w0 - 4;
            stage = zero8();
            if ((unsigned)gy < 64u && (unsigned)gx < 64u) {
                long gr = (long)(bb * 4096 + gy * 64 + gx) * 384;
                stage = ld8(kvbuf + gr + (isV ? 192 : 0) + head * 32 + dq * 8);
            }
        }

        f32x4 s[4];
#pragma unroll
        for (int kt = 0; kt < 4; ++kt) {
            bf16x8 kf = ld8(&Kc[cur][kt * 16 + llo][quad * 8]);
            f32x4 zc;
            zc[0] = 0.f; zc[1] = 0.f; zc[2] = 0.f; zc[3] = 0.f;
            s[kt] = MFMA16(kf, qf, zc);
        }

#pragma unroll
        for (int kt = 0; kt < 4; ++kt) {
            bf16x4 bv = ld4(bbase + (c * 4 + kt) * 256);
#pragma unroll
            for (int r = 0; r < 4; ++r) s[kt][r] += (float)bv[r];
        }

        float mx = s[0][0];
#pragma unroll
        for (int kt = 0; kt < 4; ++kt)
#pragma unroll
            for (int r = 0; r < 4; ++r) mx = fmaxf(mx, s[kt][r]);
        mx = fmaxf(mx, __shfl_xor(mx, 16));
        mx = fmaxf(mx, __shfl_xor(mx, 32));
        float m_new = fmaxf(m_run, mx);
        float alpha = __expf(m_run - m_new);
        float ls = 0.f;
#pragma unroll
        for (int kt = 0; kt < 4; ++kt)
#pragma unroll
            for (int r = 0; r < 4; ++r) {
                float p = __expf(s[kt][r] - m_new);
                s[kt][r] = p;
                ls += p;
            }
        ls += __shfl_xor(ls, 16);
        ls += __shfl_xor(ls, 32);
        l_run = l_run * alpha + ls;
        m_run = m_new;

#pragma unroll
        for (int r = 0; r < 4; ++r) {
            float a = __shfl(alpha, quad * 4 + r);
            o[0][r] *= a;
            o[1][r] *= a;
        }

#pragma unroll
        for (int kt = 0; kt < 4; ++kt) {
            bf16x4 pv;
#pragma unroll
            for (int r = 0; r < 4; ++r) pv[r] = (bf16)s[kt][r];
            *reinterpret_cast<bf16x4*>(&Ps[wave][llo][kt * 16 + quad * 4]) = pv;
        }

#pragma unroll
        for (int kt2 = 0; kt2 < 2; ++kt2) {
            bf16x8 pa = ld8(&Ps[wave][llo][kt2 * 32 + quad * 8]);
#pragma unroll
            for (int n2 = 0; n2 < 2; ++n2) {
                bf16x8 vb = ld8_b32(&Vt[cur][n2 * 16 + llo][kt2 * 32 + quad * 8]);
                o[n2] = MFMA16(pa, vb, o[n2]);
            }
        }

        if (c < 8) {
            if (!isV) {
                *reinterpret_cast<bf16x8*>(&Kc[1 - cur][tloc][dq * 8]) = stage;
            } else {
#pragma unroll
                for (int j = 0; j < 8; ++j) Vt[1 - cur][dq * 8 + j][tloc] = stage[j];
            }
            __syncthreads();
        }
    }

    float linv = 1.f / l_run;
#pragma unroll
    for (int r = 0; r < 4; ++r) {
        float li = __shfl(linv, quad * 4 + r);
        int q = qbase + quad * 4 + r;
        int gr = bb * 4096 + (wi * 16 + (q >> 4)) * 64 + (wj * 16 + (q & 15));
#pragma unroll
        for (int n2 = 0; n2 < 2; ++n2)
            obuf[(long)gr * 192 + head * 32 + n2 * 16 + llo] = (bf16)(o[n2][r] * li);
    }
}

// ---------------------------------------------------------------------------
// Fused proj + bias + residual + LN2 (unchanged structure).
// ---------------------------------------------------------------------------
__global__ __launch_bounds__(256, 3) void gemm_projln(
    const bf16* __restrict__ obuf, const bf16* __restrict__ wproj,
    const float* __restrict__ proj_b, const float* __restrict__ x,
    const float* __restrict__ g, const float* __restrict__ bln,
    float* __restrict__ xo, bf16* __restrict__ xn2)
{
    const int tid = threadIdx.x, wave = tid >> 6, lane = tid & 63;
    const int llo = lane & 15, quad = lane >> 4;
    const int mbase = blockIdx.x * 64;

    __shared__ __align__(16) bf16 Sa[64 * 200];
    __shared__ __align__(16) bf16 Sb[64 * 200];
    stage_tile<64, 192, 192, 256>(obuf + (long)mbase * 192, Sa, tid);
    bf16x8 wreg[6];
    load_chunk_g<64, 192, 192, 256>(wproj, wreg, tid);

    f32x4 acc[12];
#pragma unroll
    for (int nt = 0; nt < 12; ++nt)
#pragma unroll
        for (int r = 0; r < 4; ++r) acc[nt][r] = 0.f;

    for (int nc = 0; nc < 3; ++nc) {
        if (nc) __syncthreads();
        store_chunk_l<64, 192, 256>(Sb, wreg, tid);
        __syncthreads();
        if (nc < 2) load_chunk_g<64, 192, 192, 256>(wproj + (long)(nc + 1) * 64 * 192, wreg, tid);
#pragma unroll
        for (int kt = 0; kt < 6; ++kt) {
            bf16x8 a = ld8(Sa + (wave * 16 + llo) * 200 + kt * 32 + quad * 8);
#pragma unroll
            for (int nt = 0; nt < 4; ++nt) {
                bf16x8 b = ld8(Sb + (nt * 16 + llo) * 200 + kt * 32 + quad * 8);
                acc[nc * 4 + nt] = MFMA16(a, b, acc[nc * 4 + nt]);
            }
        }
    }

#pragma unroll
    for (int r = 0; r < 4; ++r) {
        int m = mbase + wave * 16 + quad * 4 + r;
        float v[12];
        float sum = 0.f, sq = 0.f;
#pragma unroll
        for (int nt = 0; nt < 12; ++nt) {
            int n = nt * 16 + llo;
            float val = 0.f;
            if (n < 180) val = acc[nt][r] + proj_b[n] + x[(long)m * 180 + n];
            v[nt] = val;
            sum += val; sq += val * val;
        }
#pragma unroll
        for (int msk = 1; msk <= 8; msk <<= 1) {
            sum += __shfl_xor(sum, msk);
            sq  += __shfl_xor(sq, msk);
        }
        float mean = sum * (1.f / 180.f);
        float var = sq * (1.f / 180.f) - mean * mean;
        float rs = rsqrtf(var + 1e-5f);
#pragma unroll
        for (int nt = 0; nt < 12; ++nt) {
            int n = nt * 16 + llo;
            if (n < 180) {
                xo[(long)m * 180 + n] = v[nt];
                xn2[(long)m * 192 + n] = (bf16)((v[nt] - mean) * rs * g[n] + bln[n]);
            } else {
                xn2[(long)m * 192 + n] = (bf16)0.f;
            }
        }
    }
}

// ---------------------------------------------------------------------------
// fc1 v3: 512 threads, 128-row M-tile, 3 N-subrounds; grid (128, 4).
// out = gelu(v) bf16 -> hmid[.][736].
// ---------------------------------------------------------------------------
__global__ __launch_bounds__(512, 4) void gemm_fc1(
    const bf16* __restrict__ A, const bf16* __restrict__ W,
    const float* __restrict__ bias, bf16* __restrict__ outp)
{
    const int tid = threadIdx.x, wave = tid >> 6, lane = tid & 63;
    const int llo = lane & 15, quad = lane >> 4;
    const int tm = blockIdx.x * 128;
    const int bz = blockIdx.y;
    const bf16* Wbase = W + (long)bz * 3 * 64 * 192;

    __shared__ __align__(16) bf16 Sa[128 * 200];
    __shared__ __align__(16) bf16 Sb[64 * 200];
    stage_tile<128, 192, 192, 512>(A + (long)tm * 192, Sa, tid);
    bf16x8 wreg[3];
    load_chunk_g<64, 192, 192, 512>(Wbase, wreg, tid);

    for (int s = 0; s < 3; ++s) {
        if (s) __syncthreads();
        store_chunk_l<64, 192, 512>(Sb, wreg, tid);
        __syncthreads();
        if (s < 2) load_chunk_g<64, 192, 192, 512>(Wbase + (long)(s + 1) * 64 * 192, wreg, tid);

        f32x4 acc[4];
#pragma unroll
        for (int nt = 0; nt < 4; ++nt)
#pragma unroll
            for (int r = 0; r < 4; ++r) acc[nt][r] = 0.f;
#pragma unroll
        for (int kt = 0; kt < 6; ++kt) {
            bf16x8 a = ld8(Sa + (wave * 16 + llo) * 200 + kt * 32 + quad * 8);
#pragma unroll
            for (int nt = 0; nt < 4; ++nt) {
                bf16x8 b = ld8(Sb + (nt * 16 + llo) * 200 + kt * 32 + quad * 8);
                acc[nt] = MFMA16(a, b, acc[nt]);
            }
        }

        const int nb = (bz * 3 + s) * 64;
#pragma unroll
        for (int nt = 0; nt < 4; ++nt) {
            int n = nb + nt * 16 + llo;
            if (n >= 720) continue;
            float bv = bias[n];
#pragma unroll
            for (int r = 0; r < 4; ++r) {
                int m = tm + wave * 16 + quad * 4 + r;
                float v = acc[nt][r] + bv;
                float gel = 0.5f * v * (1.f + erff(v * 0.7071067811865475f));
                outp[(long)m * 736 + n] = (bf16)gel;
            }
        }
    }
}

// ---------------------------------------------------------------------------
// fc2 (unchanged structure): 64x64 tile, K chunks 192/192/192/160 with
// register prefetch. fp32 out + residual.
// ---------------------------------------------------------------------------
__global__ __launch_bounds__(256, 4) void gemm_fc2(
    const bf16* __restrict__ A, const bf16* __restrict__ W,
    const float* __restrict__ bias, const float* __restrict__ resid,
    float* __restrict__ outp)
{
    const int tid = threadIdx.x, wave = tid >> 6, lane = tid & 63;
    const int llo = lane & 15, quad = lane >> 4;
    const int tm = blockIdx.x * 64;
    const int tn = blockIdx.y * 64;

    __shared__ __align__(16) bf16 Sa[64 * 200];
    __shared__ __align__(16) bf16 Sb[64 * 200];

    const bf16* Ap = A + (long)tm * 736;
    const bf16* Wp = W + (long)tn * 736;

    bf16x8 ar[6], wr[6];
    load_chunk_g<64, 192, 736, 256>(Ap, ar, tid);
    load_chunk_g<64, 192, 736, 256>(Wp, wr, tid);

    f32x4 acc[4];
#pragma unroll
    for (int nt = 0; nt < 4; ++nt)
#pragma unroll
        for (int r = 0; r < 4; ++r) acc[nt][r] = 0.f;

#pragma unroll
    for (int c = 0; c < 4; ++c) {
        if (c) __syncthreads();
        if (c < 3) {
            store_chunk_l<64, 192, 256>(Sa, ar, tid);
            store_chunk_l<64, 192, 256>(Sb, wr, tid);
        } else {
            store_chunk_l<64, 160, 256>(Sa, ar, tid);
            store_chunk_l<64, 160, 256>(Sb, wr, tid);
        }
        __syncthreads();
        if (c < 2) {
            load_chunk_g<64, 192, 736, 256>(Ap + (c + 1) * 192, ar, tid);
            load_chunk_g<64, 192, 736, 256>(Wp + (c + 1) * 192, wr, tid);
        } else if (c == 2) {
            load_chunk_g<64, 160, 736, 256>(Ap + 576, ar, tid);
            load_chunk_g<64, 160, 736, 256>(Wp + 576, wr, tid);
        }
        const int nkt = (c == 3) ? 5 : 6;
        for (int kt = 0; kt < nkt; ++kt) {
            bf16x8 a = ld8(Sa + (wave * 16 + llo) * 200 + kt * 32 + quad * 8);
#pragma unroll
            for (int nt = 0; nt < 4; ++nt) {
                bf16x8 b = ld8(Sb + (nt * 16 + llo) * 200 + kt * 32 + quad * 8);
                acc[nt] = MFMA16(a, b, acc[nt]);
            }
        }
    }

#pragma unroll
    for (int nt = 0; nt < 4; ++nt)
#pragma unroll
        for (int r = 0; r < 4; ++r) {
            int m = tm + wave * 16 + quad * 4 + r;
            int n = tn + nt * 16 + llo;
            if (n >= 180) continue;
            float v = acc[nt][r] + bias[n];
            outp[(long)m * 180 + n] = v + resid[(long)m * 180 + n];
        }
}

// ---------------------------------------------------------------------------
extern "C" void kernel_launch(void* const* d_in, const int* in_sizes, int n_in,
                              void* d_out, int out_size, void* d_ws, size_t ws_size,
                              hipStream_t stream) {
    const float* x      = (const float*)d_in[0];
    const float* y      = (const float*)d_in[1];
    const float* n1g    = (const float*)d_in[2];
    const float* n1b    = (const float*)d_in[3];
    const float* kv_w   = (const float*)d_in[4];
    const float* kv_b   = (const float*)d_in[5];
    const float* q_w    = (const float*)d_in[6];
    const float* q_b    = (const float*)d_in[7];
    const float* rpb    = (const float*)d_in[8];
    const float* proj_w = (const float*)d_in[9];
    const float* proj_b = (const float*)d_in[10];
    const float* n2g    = (const float*)d_in[11];
    const float* n2b    = (const float*)d_in[12];
    const float* fc1_w  = (const float*)d_in[13];
    const float* fc1_b  = (const float*)d_in[14];
    const float* fc2_w  = (const float*)d_in[15];
    const float* fc2_b  = (const float*)d_in[16];
    const int*   rpi    = (const int*)d_in[17];

    char* ws = (char*)d_ws;
    bf16* xn    = (bf16*)(ws + 0);          // [32768][192] = xn + yn
    bf16* yn    = (bf16*)(ws + 6291456);
    bf16* qbuf  = (bf16*)(ws + 12582912);   // [16384][192]
    bf16* kvbuf = (bf16*)(ws + 18874368);   // [16384][384]
    bf16* obuf  = (bf16*)(ws + 31457280);   // [16384][192]
    float* xo   = (float*)(ws + 37748736);  // [16384][180] fp32
    bf16* biast = (bf16*)(ws + 49545216);   // [6][16][36][64][4]
    bf16* wkv   = (bf16*)(ws + 51314688);
    bf16* wq    = (bf16*)(ws + 51462144);
    bf16* wproj = (bf16*)(ws + 51560448);
    bf16* wfc1  = (bf16*)(ws + 51658752);
    bf16* wfc2  = (bf16*)(ws + 51953664);
    bf16* hmid  = (bf16*)(ws + 6291456);    // reuse yn/qbuf/kvbuf (dead post-attn)
    bf16* xn2   = xn;                       // xn dead after gemm_kvq

    fused_pre<<<13632, 256, 0, stream>>>(x, y, n1g, n1b, xn,
                                         kv_w, q_w, proj_w, fc1_w, fc2_w, rpb, rpi,
                                         wkv, wq, wproj, wfc1, wfc2, biast);
    gemm_kvq<<<dim3(128, 3), 512, 0, stream>>>(xn, yn, wkv, wq, kv_b, q_b, kvbuf, qbuf);
    attn_kernel<<<768, 512, 0, stream>>>(qbuf, kvbuf, biast, obuf);
    gemm_projln<<<256, 256, 0, stream>>>(obuf, wproj, proj_b, x, n2g, n2b, xo, xn2);
    gemm_fc1<<<dim3(128, 4), 512, 0, stream>>>(xn2, wfc1, fc1_b, hmid);
    gemm_fc2<<<dim3(256, 3), 256, 0, stream>>>(hmid, wfc2, fc2_b, xo, (float*)d_out);
}